// Round 1
// baseline (2275.896 us; speedup 1.0000x reference)
//
#include <hip/hip_runtime.h>
#include <hip/hip_bf16.h>
#include <math.h>

// Problem constants
constexpr int B  = 2;
constexpr int L  = 4096;
constexpr int C  = 256;
constexpr int H  = 8;
constexpr int D  = 32;          // head dim
constexpr int M  = B * L;       // 8192 rows
constexpr int GK = 256;         // GEMM K (= C)
constexpr int SPLIT = 2;        // key-split for attention occupancy
constexpr int KSPAN = L / SPLIT;
constexpr int NQ = B * H * L;   // total queries = 65536

// ---------------------------------------------------------------------------
// fp32 tiled GEMM: out[M,N] = A[M,256] @ W[256,N], all row-major.
// BM=128, BN=64, BK=32, 128 threads, 8x8 per thread.
// ---------------------------------------------------------------------------
__global__ __launch_bounds__(128) void gemm_f32(const float* __restrict__ A,
                                                const float* __restrict__ W,
                                                float* __restrict__ out,
                                                int N) {
    constexpr int BM = 128, BN = 64, BK = 32, TM = 8, TN = 8;
    __shared__ float As[BK][BM + 4];
    __shared__ float Ws[BK][BN + 4];

    const int tid = threadIdx.x;        // 0..127
    const int bm0 = blockIdx.x * BM;
    const int bn0 = blockIdx.y * BN;
    const int tx  = tid & 7;            // n-dir
    const int ty  = tid >> 3;           // m-dir (0..15)

    float acc[TM][TN] = {};

    for (int k0 = 0; k0 < GK; k0 += BK) {
        // A tile (128x32), store transposed As[k][m]
        #pragma unroll
        for (int i = 0; i < 8; ++i) {
            int flat = tid + i * 128;          // float4 slot 0..1023
            int row  = flat >> 3;              // 0..127
            int c4   = flat & 7;               // 0..7
            float4 a = *reinterpret_cast<const float4*>(
                A + (size_t)(bm0 + row) * GK + k0 + c4 * 4);
            As[c4 * 4 + 0][row] = a.x;
            As[c4 * 4 + 1][row] = a.y;
            As[c4 * 4 + 2][row] = a.z;
            As[c4 * 4 + 3][row] = a.w;
        }
        // W tile (32x64), row-major direct
        #pragma unroll
        for (int i = 0; i < 4; ++i) {
            int flat = tid + i * 128;          // float4 slot 0..511
            int row  = flat >> 4;              // 0..31
            int c4   = flat & 15;              // 0..15
            *reinterpret_cast<float4*>(&Ws[row][c4 * 4]) =
                *reinterpret_cast<const float4*>(
                    W + (size_t)(k0 + row) * N + bn0 + c4 * 4);
        }
        __syncthreads();

        #pragma unroll
        for (int kk = 0; kk < BK; ++kk) {
            float a[TM], b[TN];
            #pragma unroll
            for (int i = 0; i < TM; i += 4)
                *reinterpret_cast<float4*>(&a[i]) =
                    *reinterpret_cast<const float4*>(&As[kk][ty * TM + i]);
            #pragma unroll
            for (int j = 0; j < TN; j += 4)
                *reinterpret_cast<float4*>(&b[j]) =
                    *reinterpret_cast<const float4*>(&Ws[kk][tx * TN + j]);
            #pragma unroll
            for (int i = 0; i < TM; ++i)
                #pragma unroll
                for (int j = 0; j < TN; ++j)
                    acc[i][j] += a[i] * b[j];
        }
        __syncthreads();
    }

    #pragma unroll
    for (int i = 0; i < TM; ++i) {
        float* orow = out + (size_t)(bm0 + ty * TM + i) * N + bn0 + tx * TN;
        #pragma unroll
        for (int j = 0; j < TN; j += 4) {
            float4 o = {acc[i][j], acc[i][j + 1], acc[i][j + 2], acc[i][j + 3]};
            *reinterpret_cast<float4*>(orow + j) = o;
        }
    }
}

// ---------------------------------------------------------------------------
// Normalize q,k per head, apply temperature to q, scatter to [b,h,l,d].
// One thread per (b,l,h) row-slice of 32.
// ---------------------------------------------------------------------------
__global__ __launch_bounds__(256) void norm_scatter(
    const float* __restrict__ q_raw,   // [M,256]
    const float* __restrict__ kv_raw,  // [M,512]
    const float* __restrict__ temp,    // [8]
    float* __restrict__ qn,            // [B,H,L,32]
    float* __restrict__ kn,            // [B,H,L,32]
    float* __restrict__ vv) {          // [B,H,L,32]
    const int idx = blockIdx.x * 256 + threadIdx.x;   // 0..65535
    const int h = idx & 7;
    const int r = idx >> 3;            // b*L + l
    const int b = r >> 12;
    const int l = r & 4095;
    const size_t dst = (((size_t)b * H + h) * L + l) * D;

    float q[D], k[D], v[D];
    #pragma unroll
    for (int d = 0; d < D; d += 4) {
        *reinterpret_cast<float4*>(&q[d]) = *reinterpret_cast<const float4*>(
            q_raw + (size_t)r * C + h * D + d);
        *reinterpret_cast<float4*>(&k[d]) = *reinterpret_cast<const float4*>(
            kv_raw + (size_t)r * (2 * C) + h * D + d);
        *reinterpret_cast<float4*>(&v[d]) = *reinterpret_cast<const float4*>(
            kv_raw + (size_t)r * (2 * C) + C + h * D + d);
    }
    float nq = 0.f, nk = 0.f;
    #pragma unroll
    for (int d = 0; d < D; ++d) { nq += q[d] * q[d]; nk += k[d] * k[d]; }
    const float sq = temp[h] / fmaxf(sqrtf(nq), 1e-12f);
    const float sk = 1.0f / fmaxf(sqrtf(nk), 1e-12f);
    #pragma unroll
    for (int d = 0; d < D; d += 4) {
        float4 oq = {q[d] * sq, q[d+1] * sq, q[d+2] * sq, q[d+3] * sq};
        float4 ok = {k[d] * sk, k[d+1] * sk, k[d+2] * sk, k[d+3] * sk};
        float4 ov = {v[d], v[d+1], v[d+2], v[d+3]};
        *reinterpret_cast<float4*>(qn + dst + d) = oq;
        *reinterpret_cast<float4*>(kn + dst + d) = ok;
        *reinterpret_cast<float4*>(vv + dst + d) = ov;
    }
}

// ---------------------------------------------------------------------------
// Flash attention, fp32, 1 query per thread, online softmax.
// Grid: (L/256, B*H, SPLIT). K/V row loads are wave-uniform (scalar path).
// Writes per-split partial (m, lsum, acc[32]).
// ---------------------------------------------------------------------------
__global__ __launch_bounds__(256) void attn_f32(
    const float* __restrict__ qn, const float* __restrict__ kn,
    const float* __restrict__ vv,
    float* __restrict__ pacc,          // [SPLIT, NQ, 32]
    float* __restrict__ pml) {         // [SPLIT, NQ, 2]
    const int qt  = blockIdx.x;        // 0..15
    const int bh  = blockIdx.y;        // 0..15
    const int sp  = blockIdx.z;        // 0..SPLIT-1
    const int tid = threadIdx.x;
    const int l   = qt * 256 + tid;
    const size_t bhL = (size_t)bh * L;

    float q[D];
    #pragma unroll
    for (int d = 0; d < D; d += 4)
        *reinterpret_cast<float4*>(&q[d]) =
            *reinterpret_cast<const float4*>(qn + (bhL + l) * D + d);

    float acc[D] = {};
    float m = -INFINITY, lsum = 0.f;
    const float* kb = kn + bhL * D;
    const float* vb = vv + bhL * D;

    const int kstart = sp * KSPAN;
    for (int kc = kstart; kc < kstart + KSPAN; kc += 8) {
        float sc[8];
        #pragma unroll
        for (int jj = 0; jj < 8; ++jj) {
            const float* kr = kb + (size_t)(kc + jj) * D;
            float s0 = 0.f, s1 = 0.f, s2 = 0.f, s3 = 0.f;
            #pragma unroll
            for (int d = 0; d < D; d += 4) {
                s0 += q[d + 0] * kr[d + 0];
                s1 += q[d + 1] * kr[d + 1];
                s2 += q[d + 2] * kr[d + 2];
                s3 += q[d + 3] * kr[d + 3];
            }
            sc[jj] = (s0 + s1) + (s2 + s3);
        }
        float cm = sc[0];
        #pragma unroll
        for (int jj = 1; jj < 8; ++jj) cm = fmaxf(cm, sc[jj]);
        const float mn = fmaxf(m, cm);
        const float scale = __expf(m - mn);   // first iter: exp(-inf)=0
        m = mn;
        lsum *= scale;
        #pragma unroll
        for (int d = 0; d < D; ++d) acc[d] *= scale;
        #pragma unroll
        for (int jj = 0; jj < 8; ++jj) {
            const float p = __expf(sc[jj] - mn);
            lsum += p;
            const float* vr = vb + (size_t)(kc + jj) * D;
            #pragma unroll
            for (int d = 0; d < D; ++d) acc[d] += p * vr[d];
        }
    }

    const size_t qg = bhL + l;                      // 0..NQ-1
    float* pa = pacc + ((size_t)sp * NQ + qg) * D;
    #pragma unroll
    for (int d = 0; d < D; d += 4) {
        float4 o = {acc[d], acc[d + 1], acc[d + 2], acc[d + 3]};
        *reinterpret_cast<float4*>(pa + d) = o;
    }
    pml[((size_t)sp * NQ + qg) * 2 + 0] = m;
    pml[((size_t)sp * NQ + qg) * 2 + 1] = lsum;
}

// ---------------------------------------------------------------------------
// Combine SPLIT partials, normalize by denom, write attnout[b,l,h*32+d].
// ---------------------------------------------------------------------------
__global__ __launch_bounds__(256) void combine(
    const float* __restrict__ pacc, const float* __restrict__ pml,
    float* __restrict__ attnout) {
    const int qg = blockIdx.x * 256 + threadIdx.x;  // 0..65535
    const float m0 = pml[(size_t)qg * 2 + 0];
    const float l0 = pml[(size_t)qg * 2 + 1];
    const float m1 = pml[((size_t)NQ + qg) * 2 + 0];
    const float l1 = pml[((size_t)NQ + qg) * 2 + 1];
    const float Mx = fmaxf(m0, m1);
    const float w0 = __expf(m0 - Mx);
    const float w1 = __expf(m1 - Mx);
    const float inv = 1.0f / (l0 * w0 + l1 * w1);

    const int bh = qg >> 12, l = qg & 4095;
    const int b = bh >> 3, h = bh & 7;
    float* op = attnout + ((size_t)(b * L + l) * C + h * D);
    const float* a0 = pacc + (size_t)qg * D;
    const float* a1 = pacc + ((size_t)NQ + qg) * D;
    #pragma unroll
    for (int d = 0; d < D; d += 4) {
        float4 x0 = *reinterpret_cast<const float4*>(a0 + d);
        float4 x1 = *reinterpret_cast<const float4*>(a1 + d);
        float4 o = {(x0.x * w0 + x1.x * w1) * inv,
                    (x0.y * w0 + x1.y * w1) * inv,
                    (x0.z * w0 + x1.z * w1) * inv,
                    (x0.w * w0 + x1.w * w1) * inv};
        *reinterpret_cast<float4*>(op + d) = o;
    }
}

// ---------------------------------------------------------------------------
extern "C" void kernel_launch(void* const* d_in, const int* in_sizes, int n_in,
                              void* d_out, int out_size, void* d_ws, size_t ws_size,
                              hipStream_t stream) {
    const float* x    = (const float*)d_in[0];
    const float* y    = (const float*)d_in[1];
    const float* Wq   = (const float*)d_in[2];
    const float* Wkv  = (const float*)d_in[3];
    const float* Wo   = (const float*)d_in[4];
    const float* temp = (const float*)d_in[5];
    float* out = (float*)d_out;

    // workspace layout (floats)
    float* ws = (float*)d_ws;
    float* qn      = ws;                         // 2,097,152
    float* kn      = qn + (size_t)NQ * D;        // 2,097,152
    float* vv      = kn + (size_t)NQ * D;        // 2,097,152
    float* attnout = vv + (size_t)NQ * D;        // 2,097,152
    float* P       = attnout + (size_t)M * C;    // phase1: q_raw+kv_raw (6.29M f)
    float* q_raw   = P;                          // [M,256]
    float* kv_raw  = P + (size_t)M * C;          // [M,512]
    float* pacc    = P;                          // phase2: [SPLIT,NQ,32] (4.19M f)
    float* pml     = P + (size_t)SPLIT * NQ * D; // [SPLIT,NQ,2]  (0.26M f)

    // 1) projections
    gemm_f32<<<dim3(M / 128, C / 64), 128, 0, stream>>>(x, Wq, q_raw, C);
    gemm_f32<<<dim3(M / 128, (2 * C) / 64), 128, 0, stream>>>(y, Wkv, kv_raw, 2 * C);

    // 2) normalize + temperature + scatter to [b,h,l,d]
    norm_scatter<<<NQ / 256, 256, 0, stream>>>(q_raw, kv_raw, temp, qn, kn, vv);

    // 3) attention (key-split)
    attn_f32<<<dim3(L / 256, B * H, SPLIT), 256, 0, stream>>>(qn, kn, vv, pacc, pml);

    // 4) combine splits
    combine<<<NQ / 256, 256, 0, stream>>>(pacc, pml, attnout);

    // 5) output projection
    gemm_f32<<<dim3(M / 128, C / 64), 128, 0, stream>>>(attnout, Wo, out, C);
}

// Round 2
// 267.016 us; speedup vs baseline: 8.5235x; 8.5235x over previous
//
#include <hip/hip_runtime.h>
#include <math.h>

// Problem constants
constexpr int B  = 2;
constexpr int L  = 4096;
constexpr int C  = 256;
constexpr int H  = 8;
constexpr int D  = 32;          // head dim
constexpr int M  = B * L;       // 8192 rows
constexpr int GK = 256;         // GEMM K (= C)
constexpr int BH = B * H;       // 16
constexpr int KSPLIT = 2;       // key split for occupancy
constexpr float LOG2E = 1.4426950408889634f;

typedef short s8v __attribute__((ext_vector_type(8)));   // 8 bf16 (4 VGPR)
typedef float f4v __attribute__((ext_vector_type(4)));   // MFMA C/D frag

__device__ __forceinline__ unsigned short f2bf(float x) {
    unsigned u = __float_as_uint(x);
    u += 0x7fffu + ((u >> 16) & 1u);      // RNE
    return (unsigned short)(u >> 16);
}
__device__ __forceinline__ float bf2f(unsigned short h) {
    return __uint_as_float(((unsigned)h) << 16);
}

// ---------------------------------------------------------------------------
// fp32 tiled GEMM: out[M,N] = A[M,256] @ W[256,N], all row-major. (unchanged)
// ---------------------------------------------------------------------------
__global__ __launch_bounds__(128) void gemm_f32(const float* __restrict__ A,
                                                const float* __restrict__ W,
                                                float* __restrict__ out,
                                                int N) {
    constexpr int BM = 128, BN = 64, BK = 32, TM = 8, TN = 8;
    __shared__ float As[BK][BM + 4];
    __shared__ float Ws[BK][BN + 4];

    const int tid = threadIdx.x;
    const int bm0 = blockIdx.x * BM;
    const int bn0 = blockIdx.y * BN;
    const int tx  = tid & 7;
    const int ty  = tid >> 3;

    float acc[TM][TN] = {};

    for (int k0 = 0; k0 < GK; k0 += BK) {
        #pragma unroll
        for (int i = 0; i < 8; ++i) {
            int flat = tid + i * 128;
            int row  = flat >> 3;
            int c4   = flat & 7;
            float4 a = *reinterpret_cast<const float4*>(
                A + (size_t)(bm0 + row) * GK + k0 + c4 * 4);
            As[c4 * 4 + 0][row] = a.x;
            As[c4 * 4 + 1][row] = a.y;
            As[c4 * 4 + 2][row] = a.z;
            As[c4 * 4 + 3][row] = a.w;
        }
        #pragma unroll
        for (int i = 0; i < 4; ++i) {
            int flat = tid + i * 128;
            int row  = flat >> 4;
            int c4   = flat & 15;
            *reinterpret_cast<float4*>(&Ws[row][c4 * 4]) =
                *reinterpret_cast<const float4*>(
                    W + (size_t)(k0 + row) * N + bn0 + c4 * 4);
        }
        __syncthreads();

        #pragma unroll
        for (int kk = 0; kk < BK; ++kk) {
            float a[TM], b[TN];
            #pragma unroll
            for (int i = 0; i < TM; i += 4)
                *reinterpret_cast<float4*>(&a[i]) =
                    *reinterpret_cast<const float4*>(&As[kk][ty * TM + i]);
            #pragma unroll
            for (int j = 0; j < TN; j += 4)
                *reinterpret_cast<float4*>(&b[j]) =
                    *reinterpret_cast<const float4*>(&Ws[kk][tx * TN + j]);
            #pragma unroll
            for (int i = 0; i < TM; ++i)
                #pragma unroll
                for (int j = 0; j < TN; ++j)
                    acc[i][j] += a[i] * b[j];
        }
        __syncthreads();
    }

    #pragma unroll
    for (int i = 0; i < TM; ++i) {
        float* orow = out + (size_t)(bm0 + ty * TM + i) * N + bn0 + tx * TN;
        #pragma unroll
        for (int j = 0; j < TN; j += 4) {
            float4 o = {acc[i][j], acc[i][j + 1], acc[i][j + 2], acc[i][j + 3]};
            *reinterpret_cast<float4*>(orow + j) = o;
        }
    }
}

// ---------------------------------------------------------------------------
// Normalize q,k per head; fold temperature*log2(e) into q; split each into
// bf16 hi/lo parts; write row-major [bh][l][32].
// Thread mapping: h = idx>>13 so consecutive lanes write consecutive rows.
// ---------------------------------------------------------------------------
__global__ __launch_bounds__(256) void norm_split(
    const float* __restrict__ q_raw,   // [M,256]
    const float* __restrict__ kv_raw,  // [M,512]
    const float* __restrict__ temp,    // [8]
    unsigned short* __restrict__ qhg, unsigned short* __restrict__ qlg,
    unsigned short* __restrict__ khg, unsigned short* __restrict__ klg) {
    const int idx = blockIdx.x * 256 + threadIdx.x;   // 0..65535
    const int h = idx >> 13;           // 0..7
    const int r = idx & 8191;          // b*L + l
    const int b = r >> 12;
    const int l = r & 4095;
    const size_t dst = (((size_t)(b * H + h)) * L + l) * D;

    float q[D], k[D];
    #pragma unroll
    for (int d = 0; d < D; d += 4) {
        *reinterpret_cast<float4*>(&q[d]) = *reinterpret_cast<const float4*>(
            q_raw + (size_t)r * C + h * D + d);
        *reinterpret_cast<float4*>(&k[d]) = *reinterpret_cast<const float4*>(
            kv_raw + (size_t)r * (2 * C) + h * D + d);
    }
    float nq = 0.f, nk = 0.f;
    #pragma unroll
    for (int d = 0; d < D; ++d) { nq += q[d] * q[d]; nk += k[d] * k[d]; }
    const float sq = temp[h] * LOG2E / fmaxf(sqrtf(nq), 1e-12f);
    const float sk = 1.0f / fmaxf(sqrtf(nk), 1e-12f);

    unsigned short qh[D], ql[D], kh[D], kl[D];
    #pragma unroll
    for (int d = 0; d < D; ++d) {
        float qs = q[d] * sq;
        unsigned short hq = f2bf(qs);
        qh[d] = hq; ql[d] = f2bf(qs - bf2f(hq));
        float ks = k[d] * sk;
        unsigned short hk = f2bf(ks);
        kh[d] = hk; kl[d] = f2bf(ks - bf2f(hk));
    }
    #pragma unroll
    for (int i = 0; i < 4; ++i) {
        uint4 a, bb, cc, dd;
        #define PK(arr, w, j) w = (unsigned)arr[i*8+2*j] | ((unsigned)arr[i*8+2*j+1] << 16)
        PK(qh, a.x, 0); PK(qh, a.y, 1); PK(qh, a.z, 2); PK(qh, a.w, 3);
        PK(ql, bb.x, 0); PK(ql, bb.y, 1); PK(ql, bb.z, 2); PK(ql, bb.w, 3);
        PK(kh, cc.x, 0); PK(kh, cc.y, 1); PK(kh, cc.z, 2); PK(kh, cc.w, 3);
        PK(kl, dd.x, 0); PK(kl, dd.y, 1); PK(kl, dd.z, 2); PK(kl, dd.w, 3);
        #undef PK
        *reinterpret_cast<uint4*>(qhg + dst + i * 8) = a;
        *reinterpret_cast<uint4*>(qlg + dst + i * 8) = bb;
        *reinterpret_cast<uint4*>(khg + dst + i * 8) = cc;
        *reinterpret_cast<uint4*>(klg + dst + i * 8) = dd;
    }
}

// ---------------------------------------------------------------------------
// Build vT[bh][d][slot]: bf16 V transposed, with per-32-key-chunk interleave:
// within chunk, slot 2p <- key p, slot 2p+1 <- key p+16  (p = 0..15).
// This matches the P-fragment pairing in attn_mfma so PV contracts correctly.
// ---------------------------------------------------------------------------
__global__ __launch_bounds__(256) void vT_prep(const float* __restrict__ kv_raw,
                                               unsigned short* __restrict__ vT) {
    __shared__ unsigned short lt[32][136];   // [d][key_local], padded
    const int kb = blockIdx.x * 128;
    const int bh = blockIdx.y;
    const int b = bh >> 3, h = bh & 7;
    const int t = threadIdx.x;

    { // phase 1: load V rows, convert bf16, store transposed in LDS
        const int key = kb + (t >> 1);
        const int dh  = t & 1;
        const float* src = kv_raw + ((size_t)(b * L + key)) * (2 * C) + C + h * D + dh * 16;
        #pragma unroll
        for (int i = 0; i < 16; ++i)
            lt[dh * 16 + i][t >> 1] = f2bf(src[i]);
    }
    __syncthreads();
    { // phase 2: write coalesced, interleave-permuted rows
        const int d  = t >> 3;
        const int sg = t & 7;
        unsigned ow[8];
        #pragma unroll
        for (int j = 0; j < 8; ++j) {
            int s0 = sg * 16 + 2 * j, s1 = s0 + 1;
            int lc0 = s0 >> 5, ws0 = s0 & 31;
            int lc1 = s1 >> 5, ws1 = s1 & 31;
            int k0 = lc0 * 32 + (ws0 >> 1) + (ws0 & 1) * 16;
            int k1 = lc1 * 32 + (ws1 >> 1) + (ws1 & 1) * 16;
            ow[j] = (unsigned)lt[d][k0] | ((unsigned)lt[d][k1] << 16);
        }
        const size_t dst = ((size_t)(bh * D + d)) * L + kb + sg * 16;
        uint4 u0 = {ow[0], ow[1], ow[2], ow[3]};
        uint4 u1 = {ow[4], ow[5], ow[6], ow[7]};
        *reinterpret_cast<uint4*>(vT + dst)     = u0;
        *reinterpret_cast<uint4*>(vT + dst + 8) = u1;
    }
}

// ---------------------------------------------------------------------------
// MFMA flash attention. Block = 4 waves, each wave owns 32 q rows.
// Split-bf16 QK^T (3 MFMAs / 16x16 tile), exp2 (bounded scores: no max),
// P -> bf16 pairs -> wave-private LDS -> A-frag; PV in plain bf16.
// Grid (L/128, BH, KSPLIT); partials (unnormalized acc + l) to pacc/pl.
// ---------------------------------------------------------------------------
__global__ __launch_bounds__(256) void attn_mfma(
    const unsigned short* __restrict__ qhg, const unsigned short* __restrict__ qlg,
    const unsigned short* __restrict__ khg, const unsigned short* __restrict__ klg,
    const unsigned short* __restrict__ vT,
    float* __restrict__ pacc,          // [KSPLIT][BH][L][32]
    float* __restrict__ pl) {          // [KSPLIT][BH][L]
    const int qb = blockIdx.x, bh = blockIdx.y, sp = blockIdx.z;
    const int tid  = threadIdx.x;
    const int wv   = tid >> 6;
    const int lane = tid & 63;
    const int col  = lane & 15;
    const int grp  = lane >> 4;

    __shared__ __align__(16) unsigned P_lds[4][32][20];  // per-wave, 80B rows

    const int q0 = qb * 128 + wv * 32;
    const size_t qoff = ((size_t)bh * L + q0 + col) * D + grp * 8;
    s8v qhf[2], qlf[2];
    qhf[0] = *reinterpret_cast<const s8v*>(qhg + qoff);
    qhf[1] = *reinterpret_cast<const s8v*>(qhg + qoff + 16 * D);
    qlf[0] = *reinterpret_cast<const s8v*>(qlg + qoff);
    qlf[1] = *reinterpret_cast<const s8v*>(qlg + qoff + 16 * D);

    const f4v fz = {0.f, 0.f, 0.f, 0.f};
    f4v acc[2][2] = {{fz, fz}, {fz, fz}};
    float ls[2][4] = {};

    const size_t kbase = (size_t)bh * L * D;
    const int kstart = sp * (L / KSPLIT);

    for (int c = 0; c < L / KSPLIT; c += 32) {
        const int kidx = kstart + c;
        const size_t ko = kbase + (size_t)(kidx + col) * D + grp * 8;
        s8v kh0 = *reinterpret_cast<const s8v*>(khg + ko);
        s8v kh1 = *reinterpret_cast<const s8v*>(khg + ko + 16 * D);
        s8v kl0 = *reinterpret_cast<const s8v*>(klg + ko);
        s8v kl1 = *reinterpret_cast<const s8v*>(klg + ko + 16 * D);
        const size_t vo = kbase + (size_t)col * L + kidx + grp * 8;
        s8v v0 = *reinterpret_cast<const s8v*>(vT + vo);
        s8v v1 = *reinterpret_cast<const s8v*>(vT + vo + 16 * L);

        #pragma unroll
        for (int qt = 0; qt < 2; ++qt) {
            f4v s0 = __builtin_amdgcn_mfma_f32_16x16x32_bf16(qhf[qt], kh0, fz, 0, 0, 0);
            s0 = __builtin_amdgcn_mfma_f32_16x16x32_bf16(qhf[qt], kl0, s0, 0, 0, 0);
            s0 = __builtin_amdgcn_mfma_f32_16x16x32_bf16(qlf[qt], kh0, s0, 0, 0, 0);
            f4v s1 = __builtin_amdgcn_mfma_f32_16x16x32_bf16(qhf[qt], kh1, fz, 0, 0, 0);
            s1 = __builtin_amdgcn_mfma_f32_16x16x32_bf16(qhf[qt], kl1, s1, 0, 0, 0);
            s1 = __builtin_amdgcn_mfma_f32_16x16x32_bf16(qlf[qt], kh1, s1, 0, 0, 0);
            #pragma unroll
            for (int r = 0; r < 4; ++r) {
                float p0 = exp2f(s0[r]);
                float p1 = exp2f(s1[r]);
                ls[qt][r] += p0 + p1;
                P_lds[wv][qt * 16 + grp * 4 + r][col] =
                    (unsigned)f2bf(p0) | ((unsigned)f2bf(p1) << 16);
            }
        }
        #pragma unroll
        for (int qt = 0; qt < 2; ++qt) {
            s8v pa = *reinterpret_cast<const s8v*>(&P_lds[wv][qt * 16 + col][grp * 4]);
            acc[qt][0] = __builtin_amdgcn_mfma_f32_16x16x32_bf16(pa, v0, acc[qt][0], 0, 0, 0);
            acc[qt][1] = __builtin_amdgcn_mfma_f32_16x16x32_bf16(pa, v1, acc[qt][1], 0, 0, 0);
        }
    }

    // reduce l over the 16 lanes (bits 0..3) sharing each q
    #pragma unroll
    for (int qt = 0; qt < 2; ++qt)
        #pragma unroll
        for (int r = 0; r < 4; ++r) {
            float v = ls[qt][r];
            v += __shfl_xor(v, 1);
            v += __shfl_xor(v, 2);
            v += __shfl_xor(v, 4);
            v += __shfl_xor(v, 8);
            ls[qt][r] = v;
        }

    const size_t pbase = (size_t)(sp * BH + bh) * L;
    #pragma unroll
    for (int qt = 0; qt < 2; ++qt) {
        #pragma unroll
        for (int dt = 0; dt < 2; ++dt)
            #pragma unroll
            for (int r = 0; r < 4; ++r) {
                const int q = q0 + qt * 16 + grp * 4 + r;
                pacc[(pbase + q) * D + dt * 16 + col] = acc[qt][dt][r];
            }
        if (col == 0)
            #pragma unroll
            for (int r = 0; r < 4; ++r)
                pl[pbase + q0 + qt * 16 + grp * 4 + r] = ls[qt][r];
    }
}

// ---------------------------------------------------------------------------
// Combine the 2 key-splits (plain sums: no max tracking), normalize, write
// attnout[b][l][h*32+d].
// ---------------------------------------------------------------------------
__global__ __launch_bounds__(256) void combine2(
    const float* __restrict__ pacc, const float* __restrict__ pl,
    float* __restrict__ attnout) {
    const int q = blockIdx.x * 256 + threadIdx.x;      // 0..65535 (bh*L + l)
    const float inv = 1.0f / (pl[q] + pl[(size_t)BH * L + q]);
    const int bh = q >> 12, lq = q & 4095;
    const int b = bh >> 3, h = bh & 7;
    const float* a0 = pacc + (size_t)q * D;
    const float* a1 = pacc + ((size_t)BH * L + q) * D;
    float* op = attnout + ((size_t)(b * L + lq)) * C + h * D;
    #pragma unroll
    for (int d = 0; d < D; d += 4) {
        float4 x0 = *reinterpret_cast<const float4*>(a0 + d);
        float4 x1 = *reinterpret_cast<const float4*>(a1 + d);
        float4 o = {(x0.x + x1.x) * inv, (x0.y + x1.y) * inv,
                    (x0.z + x1.z) * inv, (x0.w + x1.w) * inv};
        *reinterpret_cast<float4*>(op + d) = o;
    }
}

// ---------------------------------------------------------------------------
extern "C" void kernel_launch(void* const* d_in, const int* in_sizes, int n_in,
                              void* d_out, int out_size, void* d_ws, size_t ws_size,
                              hipStream_t stream) {
    const float* x    = (const float*)d_in[0];
    const float* y    = (const float*)d_in[1];
    const float* Wq   = (const float*)d_in[2];
    const float* Wkv  = (const float*)d_in[3];
    const float* Wo   = (const float*)d_in[4];
    const float* temp = (const float*)d_in[5];
    float* out = (float*)d_out;

    // workspace layout (bytes)
    char* w = (char*)d_ws;
    float*          q_raw  = (float*)w;                        // [0,8M)
    float*          kv_raw = (float*)(w + (8u  << 20));        // [8M,24M)
    unsigned short* qhg    = (unsigned short*)(w + (24u << 20)); // 4MB each
    unsigned short* qlg    = (unsigned short*)(w + (28u << 20));
    unsigned short* khg    = (unsigned short*)(w + (32u << 20));
    unsigned short* klg    = (unsigned short*)(w + (36u << 20));
    unsigned short* vT     = (unsigned short*)(w + (40u << 20)); // 4MB
    float*          pl     = (float*)(w + (44u << 20));          // 0.5MB
    float*          pacc   = kv_raw;                             // overlay (16MB)
    float*          attnout= q_raw;                              // overlay (8MB)

    // 1) projections (fp32)
    gemm_f32<<<dim3(M / 128, C / 64), 128, 0, stream>>>(x, Wq, q_raw, C);
    gemm_f32<<<dim3(M / 128, (2 * C) / 64), 128, 0, stream>>>(y, Wkv, kv_raw, 2 * C);

    // 2) normalize + temp*log2e fold + bf16 hi/lo split
    norm_split<<<(B * H * L) / 256, 256, 0, stream>>>(q_raw, kv_raw, temp,
                                                      qhg, qlg, khg, klg);
    // 3) V transpose (bf16, chunk-interleaved)
    vT_prep<<<dim3(L / 128, BH), 256, 0, stream>>>(kv_raw, vT);

    // 4) MFMA attention (overwrites kv_raw region with pacc)
    attn_mfma<<<dim3(L / 128, BH, KSPLIT), 256, 0, stream>>>(
        qhg, qlg, khg, klg, vT, pacc, pl);

    // 5) combine splits -> attnout (overlays q_raw)
    combine2<<<(BH * L) / 256, 256, 0, stream>>>(pacc, pl, attnout);

    // 6) output projection
    gemm_f32<<<dim3(M / 128, C / 64), 128, 0, stream>>>(attnout, Wo, out, C);
}

// Round 5
// 197.986 us; speedup vs baseline: 11.4952x; 1.3487x over previous
//
#include <hip/hip_runtime.h>
#include <math.h>

// Problem constants
constexpr int B  = 2;
constexpr int L  = 4096;
constexpr int C  = 256;
constexpr int H  = 8;
constexpr int D  = 32;          // head dim
constexpr int M  = B * L;       // 8192 rows
constexpr int BH = B * H;       // 16
constexpr int KSPLIT = 2;
constexpr int NQT = BH * L;     // 65536

typedef short    s8 __attribute__((ext_vector_type(8)));   // 8 bf16
typedef _Float16 h8 __attribute__((ext_vector_type(8)));   // 8 fp16
typedef __fp16   hp2 __attribute__((ext_vector_type(2)));  // cvt_pkrtz native type

__device__ __forceinline__ unsigned short f2bf(float x) {
    unsigned u = __float_as_uint(x);
    u += 0x7fffu + ((u >> 16) & 1u);      // RNE
    return (unsigned short)(u >> 16);
}
__device__ __forceinline__ float bf2f(unsigned short h) {
    return __uint_as_float(((unsigned)h) << 16);
}
__device__ __forceinline__ unsigned pkrtz(float a, float b) {
    union { hp2 h; unsigned u; } c;
    c.h = __builtin_amdgcn_cvt_pkrtz(a, b);   // v_cvt_pkrtz_f16_f32
    return c.u;
}
__device__ __forceinline__ unsigned short f2h(float x) {
    union { _Float16 h; unsigned short u; } c; c.h = (_Float16)x; return c.u;  // RNE
}
typedef float f4 __attribute__((ext_vector_type(4)));      // MFMA C/D

// ---------------------------------------------------------------------------
// Split fp32 -> bf16 hi/lo arrays. 8 elements per thread.
// ---------------------------------------------------------------------------
__global__ __launch_bounds__(256) void split_bf16(const float* __restrict__ in,
                                                  unsigned short* __restrict__ oh,
                                                  unsigned short* __restrict__ ol) {
    const int idx = blockIdx.x * 256 + threadIdx.x;
    float v[8];
    *reinterpret_cast<float4*>(&v[0]) = *reinterpret_cast<const float4*>(in + (size_t)idx * 8);
    *reinterpret_cast<float4*>(&v[4]) = *reinterpret_cast<const float4*>(in + (size_t)idx * 8 + 4);
    unsigned short hs[8], lo[8];
    #pragma unroll
    for (int j = 0; j < 8; ++j) {
        hs[j] = f2bf(v[j]);
        lo[j] = f2bf(v[j] - bf2f(hs[j]));
    }
    *reinterpret_cast<uint4*>(oh + (size_t)idx * 8) = *reinterpret_cast<uint4*>(hs);
    *reinterpret_cast<uint4*>(ol + (size_t)idx * 8) = *reinterpret_cast<uint4*>(lo);
}

// ---------------------------------------------------------------------------
// Transpose + bf16-split a weight matrix W[256][N] -> Wt_h/l[N][256].
// ---------------------------------------------------------------------------
__global__ __launch_bounds__(256) void prep_wt(const float* __restrict__ W,
                                               unsigned short* __restrict__ Wth,
                                               unsigned short* __restrict__ Wtl,
                                               int nlog2) {
    const int t = blockIdx.x * 256 + threadIdx.x;
    const int NN = 1 << nlog2;
    const int n = t & (NN - 1);
    const int k = t >> nlog2;            // 0..255
    const float w = W[(size_t)k * NN + n];
    const unsigned short h = f2bf(w);
    Wth[(size_t)n * 256 + k] = h;
    Wtl[(size_t)n * 256 + k] = f2bf(w - bf2f(h));
}

// ---------------------------------------------------------------------------
// Register-only bf16-split MFMA GEMM: out[M,N] = A[M,256] @ Wt[N,256]^T.
// Block = 4 waves (2x2), wave tile 32x32, block tile 64x64. No LDS/barriers.
// ---------------------------------------------------------------------------
__global__ __launch_bounds__(256) void gemm_mfma(
    const unsigned short* __restrict__ Ah, const unsigned short* __restrict__ Al,
    const unsigned short* __restrict__ Wth, const unsigned short* __restrict__ Wtl,
    float* __restrict__ out, int N) {
    const int tid  = threadIdx.x;
    const int wv   = tid >> 6;
    const int lane = tid & 63;
    const int col  = lane & 15;
    const int grp  = lane >> 4;
    const int m_base = blockIdx.x * 64 + (wv >> 1) * 32;
    const int n_base = blockIdx.y * 64 + (wv & 1) * 32;

    const f4 fz = {0.f, 0.f, 0.f, 0.f};
    f4 acc[2][2] = {{fz, fz}, {fz, fz}};

    const size_t a0 = (size_t)(m_base + col) * 256;
    const size_t w0 = (size_t)(n_base + col) * 256;

    #pragma unroll
    for (int k0 = 0; k0 < 256; k0 += 32) {
        const int ko = k0 + grp * 8;
        s8 ah[2], al[2], wh[2], wl[2];
        #pragma unroll
        for (int mt = 0; mt < 2; ++mt) {
            ah[mt] = *reinterpret_cast<const s8*>(Ah + a0 + (size_t)mt * 16 * 256 + ko);
            al[mt] = *reinterpret_cast<const s8*>(Al + a0 + (size_t)mt * 16 * 256 + ko);
        }
        #pragma unroll
        for (int nt = 0; nt < 2; ++nt) {
            wh[nt] = *reinterpret_cast<const s8*>(Wth + w0 + (size_t)nt * 16 * 256 + ko);
            wl[nt] = *reinterpret_cast<const s8*>(Wtl + w0 + (size_t)nt * 16 * 256 + ko);
        }
        #pragma unroll
        for (int mt = 0; mt < 2; ++mt)
            #pragma unroll
            for (int nt = 0; nt < 2; ++nt) {
                acc[mt][nt] = __builtin_amdgcn_mfma_f32_16x16x32_bf16(ah[mt], wh[nt], acc[mt][nt], 0, 0, 0);
                acc[mt][nt] = __builtin_amdgcn_mfma_f32_16x16x32_bf16(al[mt], wh[nt], acc[mt][nt], 0, 0, 0);
                acc[mt][nt] = __builtin_amdgcn_mfma_f32_16x16x32_bf16(ah[mt], wl[nt], acc[mt][nt], 0, 0, 0);
            }
    }

    #pragma unroll
    for (int mt = 0; mt < 2; ++mt)
        #pragma unroll
        for (int nt = 0; nt < 2; ++nt)
            #pragma unroll
            for (int r = 0; r < 4; ++r)
                out[(size_t)(m_base + mt * 16 + grp * 4 + r) * N + n_base + nt * 16 + col] =
                    acc[mt][nt][r];
}

// ---------------------------------------------------------------------------
// Normalize q,k per head; fold temperature into q; write fp16 [bh][l][32].
// ---------------------------------------------------------------------------
__global__ __launch_bounds__(256) void norm_fp16(
    const float* __restrict__ q_raw,   // [M,256]
    const float* __restrict__ kv_raw,  // [M,512]
    const float* __restrict__ temp,    // [8]
    unsigned short* __restrict__ qf, unsigned short* __restrict__ kf) {
    const int idx = blockIdx.x * 256 + threadIdx.x;   // 0..65535
    const int h = idx >> 13;           // 0..7
    const int r = idx & 8191;          // b*L + l
    const int b = r >> 12;
    const int l = r & 4095;
    const size_t dst = (((size_t)(b * H + h)) * L + l) * D;

    float q[D], k[D];
    #pragma unroll
    for (int d = 0; d < D; d += 4) {
        *reinterpret_cast<float4*>(&q[d]) = *reinterpret_cast<const float4*>(
            q_raw + (size_t)r * C + h * D + d);
        *reinterpret_cast<float4*>(&k[d]) = *reinterpret_cast<const float4*>(
            kv_raw + (size_t)r * (2 * C) + h * D + d);
    }
    float nq = 0.f, nk = 0.f;
    #pragma unroll
    for (int d = 0; d < D; ++d) { nq += q[d] * q[d]; nk += k[d] * k[d]; }
    const float sq = temp[h] / fmaxf(sqrtf(nq), 1e-12f);
    const float sk = 1.0f / fmaxf(sqrtf(nk), 1e-12f);

    unsigned short qh[D], kh[D];
    #pragma unroll
    for (int d = 0; d < D; ++d) { qh[d] = f2h(q[d] * sq); kh[d] = f2h(k[d] * sk); }
    #pragma unroll
    for (int i = 0; i < 2; ++i) {
        *reinterpret_cast<uint4*>(qf + dst + i * 16)     = *reinterpret_cast<uint4*>(&qh[i * 16]);
        *reinterpret_cast<uint4*>(qf + dst + i * 16 + 8) = *reinterpret_cast<uint4*>(&qh[i * 16 + 8]);
        *reinterpret_cast<uint4*>(kf + dst + i * 16)     = *reinterpret_cast<uint4*>(&kh[i * 16]);
        *reinterpret_cast<uint4*>(kf + dst + i * 16 + 8) = *reinterpret_cast<uint4*>(&kh[i * 16 + 8]);
    }
}

// ---------------------------------------------------------------------------
// Build vT[bh][d][slot] fp16, per-32-key-chunk interleave (slot 2p<-key p,
// slot 2p+1 <- key p+16), matching the P pairing in attn_fp16.
// ---------------------------------------------------------------------------
__global__ __launch_bounds__(256) void vT_prep(const float* __restrict__ kv_raw,
                                               unsigned short* __restrict__ vT) {
    __shared__ unsigned short lt[32][136];   // [d][key_local] fp16 bits
    const int kb = blockIdx.x * 128;
    const int bh = blockIdx.y;
    const int b = bh >> 3, h = bh & 7;
    const int t = threadIdx.x;

    {
        const int key = kb + (t >> 1);
        const int dh  = t & 1;
        const float* src = kv_raw + ((size_t)(b * L + key)) * (2 * C) + C + h * D + dh * 16;
        #pragma unroll
        for (int i = 0; i < 16; ++i)
            lt[dh * 16 + i][t >> 1] = f2h(src[i]);
    }
    __syncthreads();
    {
        const int d  = t >> 3;
        const int sg = t & 7;
        unsigned ow[8];
        #pragma unroll
        for (int j = 0; j < 8; ++j) {
            int s0 = sg * 16 + 2 * j, s1 = s0 + 1;
            int lc0 = s0 >> 5, ws0 = s0 & 31;
            int lc1 = s1 >> 5, ws1 = s1 & 31;
            int k0 = lc0 * 32 + (ws0 >> 1) + (ws0 & 1) * 16;
            int k1 = lc1 * 32 + (ws1 >> 1) + (ws1 & 1) * 16;
            ow[j] = (unsigned)lt[d][k0] | ((unsigned)lt[d][k1] << 16);
        }
        const size_t dst = ((size_t)(bh * D + d)) * L + kb + sg * 16;
        uint4 u0 = {ow[0], ow[1], ow[2], ow[3]};
        uint4 u1 = {ow[4], ow[5], ow[6], ow[7]};
        *reinterpret_cast<uint4*>(vT + dst)     = u0;
        *reinterpret_cast<uint4*>(vT + dst + 8) = u1;
    }
}

// ---------------------------------------------------------------------------
// fp16 MFMA flash attention. Block = 4 waves, wave owns 32 q rows.
// Bounded cosine scores: no running max; p = __expf(s); P via cvt_pkrtz.
// ---------------------------------------------------------------------------
__global__ __launch_bounds__(256) void attn_fp16(
    const unsigned short* __restrict__ qf, const unsigned short* __restrict__ kf,
    const unsigned short* __restrict__ vT,
    float* __restrict__ pacc,          // [KSPLIT][BH][L][32]
    float* __restrict__ pl) {          // [KSPLIT][BH][L]
    const int qb = blockIdx.x, bh = blockIdx.y, sp = blockIdx.z;
    const int tid  = threadIdx.x;
    const int wv   = tid >> 6;
    const int lane = tid & 63;
    const int col  = lane & 15;
    const int grp  = lane >> 4;

    __shared__ __align__(16) unsigned P_lds[4][32][20];  // per-wave, 80B rows

    const int q0 = qb * 128 + wv * 32;
    const size_t qoff = ((size_t)bh * L + q0 + col) * D + grp * 8;
    h8 qa[2];
    qa[0] = *reinterpret_cast<const h8*>(qf + qoff);
    qa[1] = *reinterpret_cast<const h8*>(qf + qoff + 16 * D);

    const f4 fz = {0.f, 0.f, 0.f, 0.f};
    f4 acc[2][2] = {{fz, fz}, {fz, fz}};
    float ls[2][4] = {};

    const size_t kbase = (size_t)bh * L * D;
    const int kstart = sp * (L / KSPLIT);

    for (int c = 0; c < L / KSPLIT; c += 32) {
        const int kidx = kstart + c;
        const size_t ko = kbase + (size_t)(kidx + col) * D + grp * 8;
        h8 k0 = *reinterpret_cast<const h8*>(kf + ko);
        h8 k1 = *reinterpret_cast<const h8*>(kf + ko + 16 * D);
        const size_t vo = kbase + (size_t)col * L + kidx + grp * 8;
        h8 v0 = *reinterpret_cast<const h8*>(vT + vo);
        h8 v1 = *reinterpret_cast<const h8*>(vT + vo + 16 * L);

        #pragma unroll
        for (int qt = 0; qt < 2; ++qt) {
            f4 s0 = __builtin_amdgcn_mfma_f32_16x16x32_f16(qa[qt], k0, fz, 0, 0, 0);
            f4 s1 = __builtin_amdgcn_mfma_f32_16x16x32_f16(qa[qt], k1, fz, 0, 0, 0);
            #pragma unroll
            for (int r = 0; r < 4; ++r) {
                float p0 = __expf(s0[r]);
                float p1 = __expf(s1[r]);
                ls[qt][r] += p0 + p1;
                P_lds[wv][qt * 16 + grp * 4 + r][col] = pkrtz(p0, p1);
            }
        }
        #pragma unroll
        for (int qt = 0; qt < 2; ++qt) {
            h8 pa = *reinterpret_cast<const h8*>(&P_lds[wv][qt * 16 + col][grp * 4]);
            acc[qt][0] = __builtin_amdgcn_mfma_f32_16x16x32_f16(pa, v0, acc[qt][0], 0, 0, 0);
            acc[qt][1] = __builtin_amdgcn_mfma_f32_16x16x32_f16(pa, v1, acc[qt][1], 0, 0, 0);
        }
    }

    #pragma unroll
    for (int qt = 0; qt < 2; ++qt)
        #pragma unroll
        for (int r = 0; r < 4; ++r) {
            float v = ls[qt][r];
            v += __shfl_xor(v, 1);
            v += __shfl_xor(v, 2);
            v += __shfl_xor(v, 4);
            v += __shfl_xor(v, 8);
            ls[qt][r] = v;
        }

    const size_t pbase = (size_t)(sp * BH + bh) * L;
    #pragma unroll
    for (int qt = 0; qt < 2; ++qt) {
        #pragma unroll
        for (int dt = 0; dt < 2; ++dt)
            #pragma unroll
            for (int r = 0; r < 4; ++r) {
                const int q = q0 + qt * 16 + grp * 4 + r;
                pacc[(pbase + q) * D + dt * 16 + col] = acc[qt][dt][r];
            }
        if (col == 0)
            #pragma unroll
            for (int r = 0; r < 4; ++r)
                pl[pbase + q0 + qt * 16 + grp * 4 + r] = ls[qt][r];
    }
}

// ---------------------------------------------------------------------------
// Combine key-splits, normalize, write bf16-split attnout (feeds Wo GEMM).
// ---------------------------------------------------------------------------
__global__ __launch_bounds__(256) void combine_split(
    const float* __restrict__ pacc, const float* __restrict__ pl,
    unsigned short* __restrict__ ah, unsigned short* __restrict__ al) {
    const int q = blockIdx.x * 256 + threadIdx.x;      // bh*L + l
    const float inv = 1.0f / (pl[q] + pl[(size_t)NQT + q]);
    const int bh = q >> 12, lq = q & 4095;
    const int b = bh >> 3, h = bh & 7;
    const float* a0 = pacc + (size_t)q * D;
    const float* a1 = pacc + ((size_t)NQT + q) * D;
    unsigned short oh[D], ol[D];
    #pragma unroll
    for (int d = 0; d < D; ++d) {
        float o = (a0[d] + a1[d]) * inv;
        oh[d] = f2bf(o);
        ol[d] = f2bf(o - bf2f(oh[d]));
    }
    const size_t dst = ((size_t)(b * L + lq)) * C + h * D;
    #pragma unroll
    for (int i = 0; i < 4; ++i) {
        *reinterpret_cast<uint4*>(ah + dst + i * 8) = *reinterpret_cast<uint4*>(&oh[i * 8]);
        *reinterpret_cast<uint4*>(al + dst + i * 8) = *reinterpret_cast<uint4*>(&ol[i * 8]);
    }
}

// ---------------------------------------------------------------------------
extern "C" void kernel_launch(void* const* d_in, const int* in_sizes, int n_in,
                              void* d_out, int out_size, void* d_ws, size_t ws_size,
                              hipStream_t stream) {
    const float* x    = (const float*)d_in[0];
    const float* y    = (const float*)d_in[1];
    const float* Wq   = (const float*)d_in[2];
    const float* Wkv  = (const float*)d_in[3];
    const float* Wo   = (const float*)d_in[4];
    const float* temp = (const float*)d_in[5];
    float* out = (float*)d_out;

    // workspace layout (1 MB = 1048576 B)
    char* w = (char*)d_ws;
    constexpr size_t MB = 1048576;
    unsigned short* xh     = (unsigned short*)(w + 0 * MB);      // 4MB
    unsigned short* xl     = (unsigned short*)(w + 4 * MB);
    unsigned short* yh     = (unsigned short*)(w + 8 * MB);      // 4MB (y is [M,256]!)
    unsigned short* yl     = (unsigned short*)(w + 12 * MB);
    float*          q_raw  = (float*)(w + 16 * MB);              // 8MB
    float*          kv_raw = (float*)(w + 24 * MB);              // 16MB
    unsigned short* qf     = (unsigned short*)(w + 40 * MB);     // 4MB
    unsigned short* kf     = (unsigned short*)(w + 44 * MB);     // 4MB
    unsigned short* vT     = (unsigned short*)(w + 48 * MB);     // 4MB
    float*          pl     = (float*)(w + 52 * MB);              // 0.5MB
    unsigned short* Wqt_h  = (unsigned short*)(w + 53 * MB);          // 128KB
    unsigned short* Wqt_l  = (unsigned short*)(w + 53 * MB + 131072);
    unsigned short* Wkvt_h = (unsigned short*)(w + 53 * MB + 262144); // 256KB
    unsigned short* Wkvt_l = (unsigned short*)(w + 53 * MB + 524288);
    unsigned short* Wot_h  = (unsigned short*)(w + 53 * MB + 786432); // 128KB
    unsigned short* Wot_l  = (unsigned short*)(w + 53 * MB + 917504);
    float*          pacc   = (float*)(w + 0 * MB);   // overlay [0,16.78MB)
    unsigned short* ahg    = qf;                     // overlay (qf dead after attn)
    unsigned short* alg    = kf;

    // 1) bf16 hi/lo splits of x, y  (both are [M, C] = 2,097,152 floats)
    split_bf16<<<(M * C / 8) / 256, 256, 0, stream>>>(x, xh, xl);
    split_bf16<<<(M * C / 8) / 256, 256, 0, stream>>>(y, yh, yl);

    // 2) weight transpose + split (tiny)
    prep_wt<<<256, 256, 0, stream>>>(Wq,  Wqt_h,  Wqt_l,  8);
    prep_wt<<<512, 256, 0, stream>>>(Wkv, Wkvt_h, Wkvt_l, 9);
    prep_wt<<<256, 256, 0, stream>>>(Wo,  Wot_h,  Wot_l,  8);

    // 3) projections (bf16-split MFMA, fp32 out)
    gemm_mfma<<<dim3(M / 64, C / 64), 256, 0, stream>>>(xh, xl, Wqt_h, Wqt_l, q_raw, C);
    gemm_mfma<<<dim3(M / 64, 2 * C / 64), 256, 0, stream>>>(yh, yl, Wkvt_h, Wkvt_l, kv_raw, 2 * C);

    // 4) normalize + temperature fold -> fp16 q,k ; fp16 V transpose
    norm_fp16<<<(B * H * L) / 256, 256, 0, stream>>>(q_raw, kv_raw, temp, qf, kf);
    vT_prep<<<dim3(L / 128, BH), 256, 0, stream>>>(kv_raw, vT);

    // 5) fp16 MFMA attention (pacc overlays dead regions)
    attn_fp16<<<dim3(L / 128, BH, KSPLIT), 256, 0, stream>>>(qf, kf, vT, pacc, pl);

    // 6) combine splits -> bf16-split attnout (overlays qf/kf)
    combine_split<<<NQT / 256, 256, 0, stream>>>(pacc, pl, ahg, alg);

    // 7) output projection -> d_out
    gemm_mfma<<<dim3(M / 64, C / 64), 256, 0, stream>>>(ahg, alg, Wot_h, Wot_l, out, C);
}

// Round 6
// 191.934 us; speedup vs baseline: 11.8577x; 1.0315x over previous
//
#include <hip/hip_runtime.h>
#include <math.h>

// Problem constants
constexpr int B  = 2;
constexpr int L  = 4096;
constexpr int C  = 256;
constexpr int H  = 8;
constexpr int D  = 32;          // head dim
constexpr int M  = B * L;       // 8192 rows
constexpr int BH = B * H;       // 16
constexpr int KSPLIT = 2;
constexpr int NQT = BH * L;     // 65536
constexpr float LOG2E = 1.4426950408889634f;

typedef short    s8 __attribute__((ext_vector_type(8)));   // 8 bf16
typedef _Float16 h8 __attribute__((ext_vector_type(8)));   // 8 fp16
typedef __fp16   hp2 __attribute__((ext_vector_type(2)));  // cvt_pkrtz native type
typedef float    f4 __attribute__((ext_vector_type(4)));   // MFMA C/D

__device__ __forceinline__ unsigned short f2bf(float x) {
    unsigned u = __float_as_uint(x);
    u += 0x7fffu + ((u >> 16) & 1u);      // RNE
    return (unsigned short)(u >> 16);
}
__device__ __forceinline__ float bf2f(unsigned short h) {
    return __uint_as_float(((unsigned)h) << 16);
}
__device__ __forceinline__ unsigned pkrtz(float a, float b) {
    union { hp2 h; unsigned u; } c;
    c.h = __builtin_amdgcn_cvt_pkrtz(a, b);   // v_cvt_pkrtz_f16_f32
    return c.u;
}
__device__ __forceinline__ unsigned short f2h(float x) {
    union { _Float16 h; unsigned short u; } c; c.h = (_Float16)x; return c.u;  // RNE
}

// ---------------------------------------------------------------------------
// Split fp32 -> bf16 hi/lo for BOTH x and y in one dispatch. 8 elems/thread.
// ---------------------------------------------------------------------------
__global__ __launch_bounds__(256) void split_bf16_xy(
    const float* __restrict__ x, const float* __restrict__ y,
    unsigned short* __restrict__ xh, unsigned short* __restrict__ xl,
    unsigned short* __restrict__ yh, unsigned short* __restrict__ yl) {
    const int idx = blockIdx.x * 256 + threadIdx.x;   // 0..524287
    const float* in; unsigned short *oh, *ol; int i;
    if (idx < M * C / 8) { in = x; oh = xh; ol = xl; i = idx; }
    else                 { in = y; oh = yh; ol = yl; i = idx - M * C / 8; }
    float v[8];
    *reinterpret_cast<float4*>(&v[0]) = *reinterpret_cast<const float4*>(in + (size_t)i * 8);
    *reinterpret_cast<float4*>(&v[4]) = *reinterpret_cast<const float4*>(in + (size_t)i * 8 + 4);
    unsigned short hs[8], lo[8];
    #pragma unroll
    for (int j = 0; j < 8; ++j) {
        hs[j] = f2bf(v[j]);
        lo[j] = f2bf(v[j] - bf2f(hs[j]));
    }
    *reinterpret_cast<uint4*>(oh + (size_t)i * 8) = *reinterpret_cast<uint4*>(hs);
    *reinterpret_cast<uint4*>(ol + (size_t)i * 8) = *reinterpret_cast<uint4*>(lo);
}

// ---------------------------------------------------------------------------
// Transpose + bf16-split ALL THREE weight matrices in one dispatch.
// ---------------------------------------------------------------------------
__global__ __launch_bounds__(256) void prep_wt_all(
    const float* __restrict__ Wq, const float* __restrict__ Wkv, const float* __restrict__ Wo,
    unsigned short* __restrict__ Wqt_h, unsigned short* __restrict__ Wqt_l,
    unsigned short* __restrict__ Wkvt_h, unsigned short* __restrict__ Wkvt_l,
    unsigned short* __restrict__ Wot_h, unsigned short* __restrict__ Wot_l) {
    const int t = blockIdx.x * 256 + threadIdx.x;     // 0..262143
    const float* W; unsigned short *Oh, *Ol; int nlog2, idx;
    if (t < 65536)       { W = Wq;  Oh = Wqt_h;  Ol = Wqt_l;  nlog2 = 8; idx = t; }
    else if (t < 196608) { W = Wkv; Oh = Wkvt_h; Ol = Wkvt_l; nlog2 = 9; idx = t - 65536; }
    else                 { W = Wo;  Oh = Wot_h;  Ol = Wot_l;  nlog2 = 8; idx = t - 196608; }
    const int NN = 1 << nlog2;
    const int n = idx & (NN - 1);
    const int k = idx >> nlog2;          // 0..255
    const float w = W[(size_t)k * NN + n];
    const unsigned short h = f2bf(w);
    Oh[(size_t)n * 256 + k] = h;
    Ol[(size_t)n * 256 + k] = f2bf(w - bf2f(h));
}

// ---------------------------------------------------------------------------
// Register-only bf16-split MFMA GEMM: out[M,N] = A[M,256] @ Wt[N,256]^T.
// Block = 4 waves (2x2), wave tile 32x32, block tile 64x64. No LDS/barriers.
// ---------------------------------------------------------------------------
__global__ __launch_bounds__(256) void gemm_mfma(
    const unsigned short* __restrict__ Ah, const unsigned short* __restrict__ Al,
    const unsigned short* __restrict__ Wth, const unsigned short* __restrict__ Wtl,
    float* __restrict__ out, int N) {
    const int tid  = threadIdx.x;
    const int wv   = tid >> 6;
    const int lane = tid & 63;
    const int col  = lane & 15;
    const int grp  = lane >> 4;
    const int m_base = blockIdx.x * 64 + (wv >> 1) * 32;
    const int n_base = blockIdx.y * 64 + (wv & 1) * 32;

    const f4 fz = {0.f, 0.f, 0.f, 0.f};
    f4 acc[2][2] = {{fz, fz}, {fz, fz}};

    const size_t a0 = (size_t)(m_base + col) * 256;
    const size_t w0 = (size_t)(n_base + col) * 256;

    #pragma unroll
    for (int k0 = 0; k0 < 256; k0 += 32) {
        const int ko = k0 + grp * 8;
        s8 ah[2], al[2], wh[2], wl[2];
        #pragma unroll
        for (int mt = 0; mt < 2; ++mt) {
            ah[mt] = *reinterpret_cast<const s8*>(Ah + a0 + (size_t)mt * 16 * 256 + ko);
            al[mt] = *reinterpret_cast<const s8*>(Al + a0 + (size_t)mt * 16 * 256 + ko);
        }
        #pragma unroll
        for (int nt = 0; nt < 2; ++nt) {
            wh[nt] = *reinterpret_cast<const s8*>(Wth + w0 + (size_t)nt * 16 * 256 + ko);
            wl[nt] = *reinterpret_cast<const s8*>(Wtl + w0 + (size_t)nt * 16 * 256 + ko);
        }
        #pragma unroll
        for (int mt = 0; mt < 2; ++mt)
            #pragma unroll
            for (int nt = 0; nt < 2; ++nt) {
                acc[mt][nt] = __builtin_amdgcn_mfma_f32_16x16x32_bf16(ah[mt], wh[nt], acc[mt][nt], 0, 0, 0);
                acc[mt][nt] = __builtin_amdgcn_mfma_f32_16x16x32_bf16(al[mt], wh[nt], acc[mt][nt], 0, 0, 0);
                acc[mt][nt] = __builtin_amdgcn_mfma_f32_16x16x32_bf16(ah[mt], wl[nt], acc[mt][nt], 0, 0, 0);
            }
    }

    #pragma unroll
    for (int mt = 0; mt < 2; ++mt)
        #pragma unroll
        for (int nt = 0; nt < 2; ++nt)
            #pragma unroll
            for (int r = 0; r < 4; ++r)
                out[(size_t)(m_base + mt * 16 + grp * 4 + r) * N + n_base + nt * 16 + col] =
                    acc[mt][nt][r];
}

// ---------------------------------------------------------------------------
// Normalize q,k per head; fold temperature*log2(e) into q; fp16 [bh][l][32].
// ---------------------------------------------------------------------------
__global__ __launch_bounds__(256) void norm_fp16(
    const float* __restrict__ q_raw,   // [M,256]
    const float* __restrict__ kv_raw,  // [M,512]
    const float* __restrict__ temp,    // [8]
    unsigned short* __restrict__ qf, unsigned short* __restrict__ kf) {
    const int idx = blockIdx.x * 256 + threadIdx.x;   // 0..65535
    const int h = idx >> 13;           // 0..7
    const int r = idx & 8191;          // b*L + l
    const int b = r >> 12;
    const int l = r & 4095;
    const size_t dst = (((size_t)(b * H + h)) * L + l) * D;

    float q[D], k[D];
    #pragma unroll
    for (int d = 0; d < D; d += 4) {
        *reinterpret_cast<float4*>(&q[d]) = *reinterpret_cast<const float4*>(
            q_raw + (size_t)r * C + h * D + d);
        *reinterpret_cast<float4*>(&k[d]) = *reinterpret_cast<const float4*>(
            kv_raw + (size_t)r * (2 * C) + h * D + d);
    }
    float nq = 0.f, nk = 0.f;
    #pragma unroll
    for (int d = 0; d < D; ++d) { nq += q[d] * q[d]; nk += k[d] * k[d]; }
    const float sq = temp[h] * LOG2E / fmaxf(sqrtf(nq), 1e-12f);  // exp2 fold
    const float sk = 1.0f / fmaxf(sqrtf(nk), 1e-12f);

    unsigned short qh[D], kh[D];
    #pragma unroll
    for (int d = 0; d < D; ++d) { qh[d] = f2h(q[d] * sq); kh[d] = f2h(k[d] * sk); }
    #pragma unroll
    for (int i = 0; i < 2; ++i) {
        *reinterpret_cast<uint4*>(qf + dst + i * 16)     = *reinterpret_cast<uint4*>(&qh[i * 16]);
        *reinterpret_cast<uint4*>(qf + dst + i * 16 + 8) = *reinterpret_cast<uint4*>(&qh[i * 16 + 8]);
        *reinterpret_cast<uint4*>(kf + dst + i * 16)     = *reinterpret_cast<uint4*>(&kh[i * 16]);
        *reinterpret_cast<uint4*>(kf + dst + i * 16 + 8) = *reinterpret_cast<uint4*>(&kh[i * 16 + 8]);
    }
}

// ---------------------------------------------------------------------------
// Build vT[bh][d][slot] fp16 with the A-frag permutation for swapped-QK PV:
// within each 32-key chunk, slot s (s=g*8+j) <- key (j>>2)*16 + g*4 + (j&3).
// ---------------------------------------------------------------------------
__global__ __launch_bounds__(256) void vT_prep(const float* __restrict__ kv_raw,
                                               unsigned short* __restrict__ vT) {
    __shared__ unsigned short lt[32][136];   // [d][key_local] fp16 bits
    const int kb = blockIdx.x * 128;
    const int bh = blockIdx.y;
    const int b = bh >> 3, h = bh & 7;
    const int t = threadIdx.x;

    {
        const int key = kb + (t >> 1);
        const int dh  = t & 1;
        const float* src = kv_raw + ((size_t)(b * L + key)) * (2 * C) + C + h * D + dh * 16;
        #pragma unroll
        for (int i = 0; i < 16; ++i)
            lt[dh * 16 + i][t >> 1] = f2h(src[i]);
    }
    __syncthreads();
    {
        const int d  = t >> 3;
        const int sg = t & 7;
        unsigned ow[8];
        #pragma unroll
        for (int j = 0; j < 8; ++j) {
            int s0 = sg * 16 + 2 * j, s1 = s0 + 1;
            // slot -> key within 128-key block: chunk*32 + (w>>3)*4 + ((w&7)>>2)*16 + (w&3)
            int w0 = s0 & 31, w1 = s1 & 31;
            int k0 = (s0 >> 5) * 32 + ((w0 >> 3) << 2) + (((w0 & 7) >> 2) << 4) + (w0 & 3);
            int k1 = (s1 >> 5) * 32 + ((w1 >> 3) << 2) + (((w1 & 7) >> 2) << 4) + (w1 & 3);
            ow[j] = (unsigned)lt[d][k0] | ((unsigned)lt[d][k1] << 16);
        }
        const size_t dst = ((size_t)(bh * D + d)) * L + kb + sg * 16;
        uint4 u0 = {ow[0], ow[1], ow[2], ow[3]};
        uint4 u1 = {ow[4], ow[5], ow[6], ow[7]};
        *reinterpret_cast<uint4*>(vT + dst)     = u0;
        *reinterpret_cast<uint4*>(vT + dst + 8) = u1;
    }
}

// ---------------------------------------------------------------------------
// fp16 MFMA flash attention, swapped-operand QK^T: S^T = mfma(K, Q) so each
// lane holds P for its own q row (col) -> P stays in registers, ZERO LDS.
// Bounded cosine scores: no running max; p = exp2(s) (log2e pre-folded in q).
// ---------------------------------------------------------------------------
__global__ __launch_bounds__(256) void attn_fp16(
    const unsigned short* __restrict__ qf, const unsigned short* __restrict__ kf,
    const unsigned short* __restrict__ vT,
    float* __restrict__ pacc,          // [KSPLIT][BH][L][32]
    float* __restrict__ pl) {          // [KSPLIT][BH][L]
    const int qb = blockIdx.x, bh = blockIdx.y, sp = blockIdx.z;
    const int tid  = threadIdx.x;
    const int wv   = tid >> 6;
    const int lane = tid & 63;
    const int col  = lane & 15;
    const int grp  = lane >> 4;

    const int q0 = qb * 128 + wv * 32;
    const size_t qoff = ((size_t)bh * L + q0 + col) * D + grp * 8;
    h8 qa[2];
    qa[0] = *reinterpret_cast<const h8*>(qf + qoff);
    qa[1] = *reinterpret_cast<const h8*>(qf + qoff + 16 * D);

    const f4 fz = {0.f, 0.f, 0.f, 0.f};
    f4 acc[2][2] = {{fz, fz}, {fz, fz}};
    float ls0 = 0.f, ls1 = 0.f;

    const size_t kbase = (size_t)bh * L * D;
    const int kstart = sp * (L / KSPLIT);

    #pragma unroll 2
    for (int c = 0; c < L / KSPLIT; c += 32) {
        const int kidx = kstart + c;
        const size_t ko = kbase + (size_t)(kidx + col) * D + grp * 8;
        h8 ka0 = *reinterpret_cast<const h8*>(kf + ko);            // keys kidx..+15
        h8 ka1 = *reinterpret_cast<const h8*>(kf + ko + 16 * D);   // keys +16..+31
        const size_t vo = kbase + (size_t)col * L + kidx + grp * 8;
        h8 v0 = *reinterpret_cast<const h8*>(vT + vo);
        h8 v1 = *reinterpret_cast<const h8*>(vT + vo + 16 * L);

        #pragma unroll
        for (int qt = 0; qt < 2; ++qt) {
            // S^T tiles: rows = keys, cols = q  (swapped operands)
            f4 s0 = __builtin_amdgcn_mfma_f32_16x16x32_f16(ka0, qa[qt], fz, 0, 0, 0);
            f4 s1 = __builtin_amdgcn_mfma_f32_16x16x32_f16(ka1, qa[qt], fz, 0, 0, 0);
            float p[8];
            #pragma unroll
            for (int r = 0; r < 4; ++r) {
                p[r]     = __builtin_amdgcn_exp2f(s0[r]);   // key = kidx + grp*4+r
                p[r + 4] = __builtin_amdgcn_exp2f(s1[r]);   // key = kidx+16 + grp*4+r
            }
            float sum = ((p[0] + p[1]) + (p[2] + p[3])) + ((p[4] + p[5]) + (p[6] + p[7]));
            if (qt == 0) ls0 += sum; else ls1 += sum;
            union { unsigned u[4]; h8 v; } pa;
            pa.u[0] = pkrtz(p[0], p[1]);
            pa.u[1] = pkrtz(p[2], p[3]);
            pa.u[2] = pkrtz(p[4], p[5]);
            pa.u[3] = pkrtz(p[6], p[7]);
            acc[qt][0] = __builtin_amdgcn_mfma_f32_16x16x32_f16(pa.v, v0, acc[qt][0], 0, 0, 0);
            acc[qt][1] = __builtin_amdgcn_mfma_f32_16x16x32_f16(pa.v, v1, acc[qt][1], 0, 0, 0);
        }
    }

    // each lane holds the partial denominator for q = col over its key subset;
    // sum across the 4 grp groups (lane bits 4,5)
    ls0 += __shfl_xor(ls0, 16); ls0 += __shfl_xor(ls0, 32);
    ls1 += __shfl_xor(ls1, 16); ls1 += __shfl_xor(ls1, 32);

    const size_t pbase = (size_t)(sp * BH + bh) * L;
    if (lane < 16) {
        pl[pbase + q0 + lane]      = ls0;
        pl[pbase + q0 + 16 + lane] = ls1;
    }
    #pragma unroll
    for (int qt = 0; qt < 2; ++qt)
        #pragma unroll
        for (int dt = 0; dt < 2; ++dt)
            #pragma unroll
            for (int r = 0; r < 4; ++r) {
                const int q = q0 + qt * 16 + grp * 4 + r;
                pacc[(pbase + q) * D + dt * 16 + col] = acc[qt][dt][r];
            }
}

// ---------------------------------------------------------------------------
// Combine key-splits, normalize, write bf16-split attnout (feeds Wo GEMM).
// ---------------------------------------------------------------------------
__global__ __launch_bounds__(256) void combine_split(
    const float* __restrict__ pacc, const float* __restrict__ pl,
    unsigned short* __restrict__ ah, unsigned short* __restrict__ al) {
    const int q = blockIdx.x * 256 + threadIdx.x;      // bh*L + l
    const float inv = 1.0f / (pl[q] + pl[(size_t)NQT + q]);
    const int bh = q >> 12, lq = q & 4095;
    const int b = bh >> 3, h = bh & 7;
    const float* a0 = pacc + (size_t)q * D;
    const float* a1 = pacc + ((size_t)NQT + q) * D;
    unsigned short oh[D], ol[D];
    #pragma unroll
    for (int d = 0; d < D; ++d) {
        float o = (a0[d] + a1[d]) * inv;
        oh[d] = f2bf(o);
        ol[d] = f2bf(o - bf2f(oh[d]));
    }
    const size_t dst = ((size_t)(b * L + lq)) * C + h * D;
    #pragma unroll
    for (int i = 0; i < 4; ++i) {
        *reinterpret_cast<uint4*>(ah + dst + i * 8) = *reinterpret_cast<uint4*>(&oh[i * 8]);
        *reinterpret_cast<uint4*>(al + dst + i * 8) = *reinterpret_cast<uint4*>(&ol[i * 8]);
    }
}

// ---------------------------------------------------------------------------
extern "C" void kernel_launch(void* const* d_in, const int* in_sizes, int n_in,
                              void* d_out, int out_size, void* d_ws, size_t ws_size,
                              hipStream_t stream) {
    const float* x    = (const float*)d_in[0];
    const float* y    = (const float*)d_in[1];
    const float* Wq   = (const float*)d_in[2];
    const float* Wkv  = (const float*)d_in[3];
    const float* Wo   = (const float*)d_in[4];
    const float* temp = (const float*)d_in[5];
    float* out = (float*)d_out;

    // workspace layout (1 MB = 1048576 B)
    char* w = (char*)d_ws;
    constexpr size_t MB = 1048576;
    unsigned short* xh     = (unsigned short*)(w + 0 * MB);      // 4MB
    unsigned short* xl     = (unsigned short*)(w + 4 * MB);
    unsigned short* yh     = (unsigned short*)(w + 8 * MB);      // 4MB
    unsigned short* yl     = (unsigned short*)(w + 12 * MB);
    float*          q_raw  = (float*)(w + 16 * MB);              // 8MB
    float*          kv_raw = (float*)(w + 24 * MB);              // 16MB
    unsigned short* qf     = (unsigned short*)(w + 40 * MB);     // 4MB
    unsigned short* kf     = (unsigned short*)(w + 44 * MB);     // 4MB
    unsigned short* vT     = (unsigned short*)(w + 48 * MB);     // 4MB
    float*          pl     = (float*)(w + 52 * MB);              // 0.5MB
    unsigned short* Wqt_h  = (unsigned short*)(w + 53 * MB);          // 128KB
    unsigned short* Wqt_l  = (unsigned short*)(w + 53 * MB + 131072);
    unsigned short* Wkvt_h = (unsigned short*)(w + 53 * MB + 262144); // 256KB
    unsigned short* Wkvt_l = (unsigned short*)(w + 53 * MB + 524288);
    unsigned short* Wot_h  = (unsigned short*)(w + 53 * MB + 786432); // 128KB
    unsigned short* Wot_l  = (unsigned short*)(w + 53 * MB + 917504);
    float*          pacc   = (float*)(w + 0 * MB);   // overlay [0,16.78MB)
    unsigned short* ahg    = qf;                     // overlay (qf dead after attn)
    unsigned short* alg    = kf;

    // 1) bf16 hi/lo splits of x and y (one dispatch)
    split_bf16_xy<<<(2 * M * C / 8) / 256, 256, 0, stream>>>(x, y, xh, xl, yh, yl);

    // 2) weight transpose + split (one dispatch)
    prep_wt_all<<<1024, 256, 0, stream>>>(Wq, Wkv, Wo, Wqt_h, Wqt_l,
                                          Wkvt_h, Wkvt_l, Wot_h, Wot_l);

    // 3) projections (bf16-split MFMA, fp32 out)
    gemm_mfma<<<dim3(M / 64, C / 64), 256, 0, stream>>>(xh, xl, Wqt_h, Wqt_l, q_raw, C);
    gemm_mfma<<<dim3(M / 64, 2 * C / 64), 256, 0, stream>>>(yh, yl, Wkvt_h, Wkvt_l, kv_raw, 2 * C);

    // 4) normalize + temp*log2e fold -> fp16 q,k ; fp16 V transpose (permuted)
    norm_fp16<<<(B * H * L) / 256, 256, 0, stream>>>(q_raw, kv_raw, temp, qf, kf);
    vT_prep<<<dim3(L / 128, BH), 256, 0, stream>>>(kv_raw, vT);

    // 5) fp16 MFMA attention, register-resident P (pacc overlays dead regions)
    attn_fp16<<<dim3(L / 128, BH, KSPLIT), 256, 0, stream>>>(qf, kf, vT, pacc, pl);

    // 6) combine splits -> bf16-split attnout (overlays qf/kf)
    combine_split<<<NQT / 256, 256, 0, stream>>>(pacc, pl, ahg, alg);

    // 7) output projection -> d_out
    gemm_mfma<<<dim3(M / 64, C / 64), 256, 0, stream>>>(ahg, alg, Wot_h, Wot_l, out, C);
}

// Round 7
// 185.355 us; speedup vs baseline: 12.2786x; 1.0355x over previous
//
#include <hip/hip_runtime.h>
#include <math.h>

// Problem constants
constexpr int B  = 2;
constexpr int L  = 4096;
constexpr int C  = 256;
constexpr int H  = 8;
constexpr int D  = 32;          // head dim
constexpr int M  = B * L;       // 8192 rows
constexpr int BH = B * H;       // 16
constexpr int KSPLIT = 4;       // key split for occupancy (8 blocks/CU)
constexpr int NQT = BH * L;     // 65536
constexpr float LOG2E = 1.4426950408889634f;

typedef short    s8 __attribute__((ext_vector_type(8)));   // 8 bf16
typedef _Float16 h8 __attribute__((ext_vector_type(8)));   // 8 fp16
typedef __fp16   hp2 __attribute__((ext_vector_type(2)));  // cvt_pkrtz native type
typedef float    f4 __attribute__((ext_vector_type(4)));   // MFMA C/D

__device__ __forceinline__ unsigned short f2bf(float x) {
    unsigned u = __float_as_uint(x);
    u += 0x7fffu + ((u >> 16) & 1u);      // RNE
    return (unsigned short)(u >> 16);
}
__device__ __forceinline__ float bf2f(unsigned short h) {
    return __uint_as_float(((unsigned)h) << 16);
}
__device__ __forceinline__ unsigned pkrtz(float a, float b) {
    union { hp2 h; unsigned u; } c;
    c.h = __builtin_amdgcn_cvt_pkrtz(a, b);   // v_cvt_pkrtz_f16_f32
    return c.u;
}
__device__ __forceinline__ unsigned short f2h(float x) {
    union { _Float16 h; unsigned short u; } c; c.h = (_Float16)x; return c.u;  // RNE
}
__device__ __forceinline__ float h2f(unsigned short u) {
    union { _Float16 h; unsigned short u; } c; c.u = u; return (float)c.h;
}

// ---------------------------------------------------------------------------
// Split fp32 -> bf16 hi/lo for BOTH x and y in one dispatch. 8 elems/thread.
// ---------------------------------------------------------------------------
__global__ __launch_bounds__(256) void split_bf16_xy(
    const float* __restrict__ x, const float* __restrict__ y,
    unsigned short* __restrict__ xh, unsigned short* __restrict__ xl,
    unsigned short* __restrict__ yh, unsigned short* __restrict__ yl) {
    const int idx = blockIdx.x * 256 + threadIdx.x;   // 0..524287
    const float* in; unsigned short *oh, *ol; int i;
    if (idx < M * C / 8) { in = x; oh = xh; ol = xl; i = idx; }
    else                 { in = y; oh = yh; ol = yl; i = idx - M * C / 8; }
    float v[8];
    *reinterpret_cast<float4*>(&v[0]) = *reinterpret_cast<const float4*>(in + (size_t)i * 8);
    *reinterpret_cast<float4*>(&v[4]) = *reinterpret_cast<const float4*>(in + (size_t)i * 8 + 4);
    unsigned short hs[8], lo[8];
    #pragma unroll
    for (int j = 0; j < 8; ++j) {
        hs[j] = f2bf(v[j]);
        lo[j] = f2bf(v[j] - bf2f(hs[j]));
    }
    *reinterpret_cast<uint4*>(oh + (size_t)i * 8) = *reinterpret_cast<uint4*>(hs);
    *reinterpret_cast<uint4*>(ol + (size_t)i * 8) = *reinterpret_cast<uint4*>(lo);
}

// ---------------------------------------------------------------------------
// Transpose + bf16-split ALL THREE weight matrices in one dispatch.
// ---------------------------------------------------------------------------
__global__ __launch_bounds__(256) void prep_wt_all(
    const float* __restrict__ Wq, const float* __restrict__ Wkv, const float* __restrict__ Wo,
    unsigned short* __restrict__ Wqt_h, unsigned short* __restrict__ Wqt_l,
    unsigned short* __restrict__ Wkvt_h, unsigned short* __restrict__ Wkvt_l,
    unsigned short* __restrict__ Wot_h, unsigned short* __restrict__ Wot_l) {
    const int t = blockIdx.x * 256 + threadIdx.x;     // 0..262143
    const float* W; unsigned short *Oh, *Ol; int nlog2, idx;
    if (t < 65536)       { W = Wq;  Oh = Wqt_h;  Ol = Wqt_l;  nlog2 = 8; idx = t; }
    else if (t < 196608) { W = Wkv; Oh = Wkvt_h; Ol = Wkvt_l; nlog2 = 9; idx = t - 65536; }
    else                 { W = Wo;  Oh = Wot_h;  Ol = Wot_l;  nlog2 = 8; idx = t - 196608; }
    const int NN = 1 << nlog2;
    const int n = idx & (NN - 1);
    const int k = idx >> nlog2;          // 0..255
    const float w = W[(size_t)k * NN + n];
    const unsigned short h = f2bf(w);
    Oh[(size_t)n * 256 + k] = h;
    Ol[(size_t)n * 256 + k] = f2bf(w - bf2f(h));
}

// ---------------------------------------------------------------------------
// Register-only bf16-split MFMA GEMM + FUSED l2-norm epilogue.
// MODE 0: q projection  -> norm * temp[h]*LOG2E -> qf[bh][l][32] fp16
// MODE 1: kv projection -> cols<256: norm -> kf ; cols>=256: plain -> vrow
// Block = 4 waves (2x2), wave tile 32x32 (= exactly one head per wave).
// ---------------------------------------------------------------------------
template <int MODE>
__global__ __launch_bounds__(256) void gemm_norm(
    const unsigned short* __restrict__ Ah, const unsigned short* __restrict__ Al,
    const unsigned short* __restrict__ Wth, const unsigned short* __restrict__ Wtl,
    const float* __restrict__ temp,
    unsigned short* __restrict__ qkf, unsigned short* __restrict__ vrow) {
    const int tid  = threadIdx.x;
    const int wv   = tid >> 6;
    const int lane = tid & 63;
    const int col  = lane & 15;
    const int grp  = lane >> 4;
    const int m_base = blockIdx.x * 64 + (wv >> 1) * 32;
    const int n_base = blockIdx.y * 64 + (wv & 1) * 32;

    const f4 fz = {0.f, 0.f, 0.f, 0.f};
    f4 acc[2][2] = {{fz, fz}, {fz, fz}};

    const size_t a0 = (size_t)(m_base + col) * 256;
    const size_t w0 = (size_t)(n_base + col) * 256;

    #pragma unroll
    for (int k0 = 0; k0 < 256; k0 += 32) {
        const int ko = k0 + grp * 8;
        s8 ah[2], al[2], wh[2], wl[2];
        #pragma unroll
        for (int mt = 0; mt < 2; ++mt) {
            ah[mt] = *reinterpret_cast<const s8*>(Ah + a0 + (size_t)mt * 16 * 256 + ko);
            al[mt] = *reinterpret_cast<const s8*>(Al + a0 + (size_t)mt * 16 * 256 + ko);
        }
        #pragma unroll
        for (int nt = 0; nt < 2; ++nt) {
            wh[nt] = *reinterpret_cast<const s8*>(Wth + w0 + (size_t)nt * 16 * 256 + ko);
            wl[nt] = *reinterpret_cast<const s8*>(Wtl + w0 + (size_t)nt * 16 * 256 + ko);
        }
        #pragma unroll
        for (int mt = 0; mt < 2; ++mt)
            #pragma unroll
            for (int nt = 0; nt < 2; ++nt) {
                acc[mt][nt] = __builtin_amdgcn_mfma_f32_16x16x32_bf16(ah[mt], wh[nt], acc[mt][nt], 0, 0, 0);
                acc[mt][nt] = __builtin_amdgcn_mfma_f32_16x16x32_bf16(al[mt], wh[nt], acc[mt][nt], 0, 0, 0);
                acc[mt][nt] = __builtin_amdgcn_mfma_f32_16x16x32_bf16(ah[mt], wl[nt], acc[mt][nt], 0, 0, 0);
            }
    }

    // fused epilogue: per-row sum of squares across the head's 32 cols
    const bool is_v = (MODE == 1) && (n_base >= 256);
    const int  nb   = is_v ? n_base - 256 : n_base;
    const int  h    = (nb >> 5) & 7;
    const float tl  = (MODE == 0) ? temp[h] * LOG2E : 1.0f;
    unsigned short* dst = is_v ? vrow : qkf;

    #pragma unroll
    for (int mt = 0; mt < 2; ++mt)
        #pragma unroll
        for (int r = 0; r < 4; ++r) {
            float scale = 1.0f;
            if (!is_v) {
                float t = acc[mt][0][r] * acc[mt][0][r] + acc[mt][1][r] * acc[mt][1][r];
                t += __shfl_xor(t, 1);
                t += __shfl_xor(t, 2);
                t += __shfl_xor(t, 4);
                t += __shfl_xor(t, 8);
                scale = tl / fmaxf(sqrtf(t), 1e-12f);
            }
            const int row = m_base + mt * 16 + grp * 4 + r;
            const int bb = row >> 12, l = row & 4095;
            const size_t base = ((size_t)(bb * H + h) * L + l) * D;
            dst[base + col]      = f2h(acc[mt][0][r] * scale);
            dst[base + 16 + col] = f2h(acc[mt][1][r] * scale);
        }
}

// ---------------------------------------------------------------------------
// Plain register-only bf16-split MFMA GEMM (output projection), fp32 out.
// ---------------------------------------------------------------------------
__global__ __launch_bounds__(256) void gemm_mfma(
    const unsigned short* __restrict__ Ah, const unsigned short* __restrict__ Al,
    const unsigned short* __restrict__ Wth, const unsigned short* __restrict__ Wtl,
    float* __restrict__ out, int N) {
    const int tid  = threadIdx.x;
    const int wv   = tid >> 6;
    const int lane = tid & 63;
    const int col  = lane & 15;
    const int grp  = lane >> 4;
    const int m_base = blockIdx.x * 64 + (wv >> 1) * 32;
    const int n_base = blockIdx.y * 64 + (wv & 1) * 32;

    const f4 fz = {0.f, 0.f, 0.f, 0.f};
    f4 acc[2][2] = {{fz, fz}, {fz, fz}};

    const size_t a0 = (size_t)(m_base + col) * 256;
    const size_t w0 = (size_t)(n_base + col) * 256;

    #pragma unroll
    for (int k0 = 0; k0 < 256; k0 += 32) {
        const int ko = k0 + grp * 8;
        s8 ah[2], al[2], wh[2], wl[2];
        #pragma unroll
        for (int mt = 0; mt < 2; ++mt) {
            ah[mt] = *reinterpret_cast<const s8*>(Ah + a0 + (size_t)mt * 16 * 256 + ko);
            al[mt] = *reinterpret_cast<const s8*>(Al + a0 + (size_t)mt * 16 * 256 + ko);
        }
        #pragma unroll
        for (int nt = 0; nt < 2; ++nt) {
            wh[nt] = *reinterpret_cast<const s8*>(Wth + w0 + (size_t)nt * 16 * 256 + ko);
            wl[nt] = *reinterpret_cast<const s8*>(Wtl + w0 + (size_t)nt * 16 * 256 + ko);
        }
        #pragma unroll
        for (int mt = 0; mt < 2; ++mt)
            #pragma unroll
            for (int nt = 0; nt < 2; ++nt) {
                acc[mt][nt] = __builtin_amdgcn_mfma_f32_16x16x32_bf16(ah[mt], wh[nt], acc[mt][nt], 0, 0, 0);
                acc[mt][nt] = __builtin_amdgcn_mfma_f32_16x16x32_bf16(al[mt], wh[nt], acc[mt][nt], 0, 0, 0);
                acc[mt][nt] = __builtin_amdgcn_mfma_f32_16x16x32_bf16(ah[mt], wl[nt], acc[mt][nt], 0, 0, 0);
            }
    }

    #pragma unroll
    for (int mt = 0; mt < 2; ++mt)
        #pragma unroll
        for (int nt = 0; nt < 2; ++nt)
            #pragma unroll
            for (int r = 0; r < 4; ++r)
                out[(size_t)(m_base + mt * 16 + grp * 4 + r) * N + n_base + nt * 16 + col] =
                    acc[mt][nt][r];
}

// ---------------------------------------------------------------------------
// Build vT[bh][d][slot] fp16 from vrow[bh][l][32] (fp16) with the A-frag
// permutation: within each 32-key chunk, slot w <- key (w>>3)*4+((w&7)>>2)*16+(w&3).
// ---------------------------------------------------------------------------
__global__ __launch_bounds__(256) void vT_prep(const unsigned short* __restrict__ vrow,
                                               unsigned short* __restrict__ vT) {
    __shared__ unsigned short lt[32][136];   // [d][key_local] fp16 bits
    const int kb = blockIdx.x * 128;
    const int bh = blockIdx.y;
    const int t = threadIdx.x;

    {
        const int key = kb + (t >> 1);
        const int dh  = t & 1;
        const unsigned short* src = vrow + ((size_t)bh * L + key) * D + dh * 16;
        unsigned short tmp[16];
        *reinterpret_cast<uint4*>(&tmp[0]) = *reinterpret_cast<const uint4*>(src);
        *reinterpret_cast<uint4*>(&tmp[8]) = *reinterpret_cast<const uint4*>(src + 8);
        #pragma unroll
        for (int i = 0; i < 16; ++i)
            lt[dh * 16 + i][t >> 1] = tmp[i];
    }
    __syncthreads();
    {
        const int d  = t >> 3;
        const int sg = t & 7;
        unsigned ow[8];
        #pragma unroll
        for (int j = 0; j < 8; ++j) {
            int s0 = sg * 16 + 2 * j, s1 = s0 + 1;
            int w0 = s0 & 31, w1 = s1 & 31;
            int k0 = (s0 >> 5) * 32 + ((w0 >> 3) << 2) + (((w0 & 7) >> 2) << 4) + (w0 & 3);
            int k1 = (s1 >> 5) * 32 + ((w1 >> 3) << 2) + (((w1 & 7) >> 2) << 4) + (w1 & 3);
            ow[j] = (unsigned)lt[d][k0] | ((unsigned)lt[d][k1] << 16);
        }
        const size_t dst = ((size_t)(bh * D + d)) * L + kb + sg * 16;
        uint4 u0 = {ow[0], ow[1], ow[2], ow[3]};
        uint4 u1 = {ow[4], ow[5], ow[6], ow[7]};
        *reinterpret_cast<uint4*>(vT + dst)     = u0;
        *reinterpret_cast<uint4*>(vT + dst + 8) = u1;
    }
}

// ---------------------------------------------------------------------------
// fp16 MFMA flash attention, swapped-operand QK^T (P register-resident, no
// LDS). KSPLIT=4 -> 2048 blocks -> 8 blocks/CU for latency hiding.
// Partials stored fp16 (RNE).
// ---------------------------------------------------------------------------
__global__ __launch_bounds__(256) void attn_fp16(
    const unsigned short* __restrict__ qf, const unsigned short* __restrict__ kf,
    const unsigned short* __restrict__ vT,
    unsigned short* __restrict__ pacc,  // [KSPLIT][NQT][32] fp16
    float* __restrict__ pl) {           // [KSPLIT][NQT]
    const int qb = blockIdx.x, bh = blockIdx.y, sp = blockIdx.z;
    const int tid  = threadIdx.x;
    const int wv   = tid >> 6;
    const int lane = tid & 63;
    const int col  = lane & 15;
    const int grp  = lane >> 4;

    const int q0 = qb * 128 + wv * 32;
    const size_t qoff = ((size_t)bh * L + q0 + col) * D + grp * 8;
    h8 qa[2];
    qa[0] = *reinterpret_cast<const h8*>(qf + qoff);
    qa[1] = *reinterpret_cast<const h8*>(qf + qoff + 16 * D);

    const f4 fz = {0.f, 0.f, 0.f, 0.f};
    f4 acc[2][2] = {{fz, fz}, {fz, fz}};
    float ls0 = 0.f, ls1 = 0.f;

    const size_t kbase = (size_t)bh * L * D;
    const int kstart = sp * (L / KSPLIT);

    #pragma unroll 2
    for (int c = 0; c < L / KSPLIT; c += 32) {
        const int kidx = kstart + c;
        const size_t ko = kbase + (size_t)(kidx + col) * D + grp * 8;
        h8 ka0 = *reinterpret_cast<const h8*>(kf + ko);            // keys kidx..+15
        h8 ka1 = *reinterpret_cast<const h8*>(kf + ko + 16 * D);   // keys +16..+31
        const size_t vo = kbase + (size_t)col * L + kidx + grp * 8;
        h8 v0 = *reinterpret_cast<const h8*>(vT + vo);
        h8 v1 = *reinterpret_cast<const h8*>(vT + vo + 16 * L);

        #pragma unroll
        for (int qt = 0; qt < 2; ++qt) {
            // S^T tiles: rows = keys, cols = q  (swapped operands)
            f4 s0 = __builtin_amdgcn_mfma_f32_16x16x32_f16(ka0, qa[qt], fz, 0, 0, 0);
            f4 s1 = __builtin_amdgcn_mfma_f32_16x16x32_f16(ka1, qa[qt], fz, 0, 0, 0);
            float p[8];
            #pragma unroll
            for (int r = 0; r < 4; ++r) {
                p[r]     = __builtin_amdgcn_exp2f(s0[r]);
                p[r + 4] = __builtin_amdgcn_exp2f(s1[r]);
            }
            float sum = ((p[0] + p[1]) + (p[2] + p[3])) + ((p[4] + p[5]) + (p[6] + p[7]));
            if (qt == 0) ls0 += sum; else ls1 += sum;
            union { unsigned u[4]; h8 v; } pa;
            pa.u[0] = pkrtz(p[0], p[1]);
            pa.u[1] = pkrtz(p[2], p[3]);
            pa.u[2] = pkrtz(p[4], p[5]);
            pa.u[3] = pkrtz(p[6], p[7]);
            acc[qt][0] = __builtin_amdgcn_mfma_f32_16x16x32_f16(pa.v, v0, acc[qt][0], 0, 0, 0);
            acc[qt][1] = __builtin_amdgcn_mfma_f32_16x16x32_f16(pa.v, v1, acc[qt][1], 0, 0, 0);
        }
    }

    // denominators: sum across the 4 grp groups (lane bits 4,5)
    ls0 += __shfl_xor(ls0, 16); ls0 += __shfl_xor(ls0, 32);
    ls1 += __shfl_xor(ls1, 16); ls1 += __shfl_xor(ls1, 32);

    const size_t pbase = (size_t)sp * NQT + (size_t)bh * L;
    if (lane < 16) {
        pl[pbase + q0 + lane]      = ls0;
        pl[pbase + q0 + 16 + lane] = ls1;
    }
    #pragma unroll
    for (int qt = 0; qt < 2; ++qt)
        #pragma unroll
        for (int dt = 0; dt < 2; ++dt)
            #pragma unroll
            for (int r = 0; r < 4; ++r) {
                const int q = q0 + qt * 16 + grp * 4 + r;
                pacc[(pbase + q) * D + dt * 16 + col] = f2h(acc[qt][dt][r]);
            }
}

// ---------------------------------------------------------------------------
// Combine 4 key-splits, normalize, write bf16-split attnout (feeds Wo GEMM).
// ---------------------------------------------------------------------------
__global__ __launch_bounds__(256) void combine_split(
    const unsigned short* __restrict__ pacc, const float* __restrict__ pl,
    unsigned short* __restrict__ ah, unsigned short* __restrict__ al) {
    const int q = blockIdx.x * 256 + threadIdx.x;      // bh*L + l
    float den = 0.f;
    #pragma unroll
    for (int sp = 0; sp < KSPLIT; ++sp) den += pl[(size_t)sp * NQT + q];
    const float inv = 1.0f / den;

    float o[D] = {};
    #pragma unroll
    for (int sp = 0; sp < KSPLIT; ++sp) {
        const unsigned short* a = pacc + ((size_t)sp * NQT + q) * D;
        unsigned short t[D];
        #pragma unroll
        for (int i = 0; i < 4; ++i)
            *reinterpret_cast<uint4*>(&t[i * 8]) = *reinterpret_cast<const uint4*>(a + i * 8);
        #pragma unroll
        for (int d = 0; d < D; ++d) o[d] += h2f(t[d]);
    }

    const int bh = q >> 12, lq = q & 4095;
    const int b = bh >> 3, h = bh & 7;
    unsigned short oh[D], ol[D];
    #pragma unroll
    for (int d = 0; d < D; ++d) {
        float v = o[d] * inv;
        oh[d] = f2bf(v);
        ol[d] = f2bf(v - bf2f(oh[d]));
    }
    const size_t dst = ((size_t)(b * L + lq)) * C + h * D;
    #pragma unroll
    for (int i = 0; i < 4; ++i) {
        *reinterpret_cast<uint4*>(ah + dst + i * 8) = *reinterpret_cast<uint4*>(&oh[i * 8]);
        *reinterpret_cast<uint4*>(al + dst + i * 8) = *reinterpret_cast<uint4*>(&ol[i * 8]);
    }
}

// ---------------------------------------------------------------------------
extern "C" void kernel_launch(void* const* d_in, const int* in_sizes, int n_in,
                              void* d_out, int out_size, void* d_ws, size_t ws_size,
                              hipStream_t stream) {
    const float* x    = (const float*)d_in[0];
    const float* y    = (const float*)d_in[1];
    const float* Wq   = (const float*)d_in[2];
    const float* Wkv  = (const float*)d_in[3];
    const float* Wo   = (const float*)d_in[4];
    const float* temp = (const float*)d_in[5];
    float* out = (float*)d_out;

    // workspace layout (1 MB = 1048576 B), max 34 MB
    char* w = (char*)d_ws;
    constexpr size_t MB = 1048576;
    unsigned short* xh     = (unsigned short*)(w + 0 * MB);      // 4MB each
    unsigned short* xl     = (unsigned short*)(w + 4 * MB);
    unsigned short* yh     = (unsigned short*)(w + 8 * MB);
    unsigned short* yl     = (unsigned short*)(w + 12 * MB);
    unsigned short* vrow   = (unsigned short*)(w + 16 * MB);     // 4MB fp16 [bh][l][32]
    unsigned short* qf     = (unsigned short*)(w + 20 * MB);     // 4MB
    unsigned short* kf     = (unsigned short*)(w + 24 * MB);     // 4MB
    unsigned short* vT     = (unsigned short*)(w + 28 * MB);     // 4MB
    unsigned short* Wqt_h  = (unsigned short*)(w + 32 * MB);          // 128KB
    unsigned short* Wqt_l  = (unsigned short*)(w + 32 * MB + 131072);
    unsigned short* Wkvt_h = (unsigned short*)(w + 32 * MB + 262144); // 256KB
    unsigned short* Wkvt_l = (unsigned short*)(w + 32 * MB + 524288);
    unsigned short* Wot_h  = (unsigned short*)(w + 32 * MB + 786432); // 128KB
    unsigned short* Wot_l  = (unsigned short*)(w + 32 * MB + 917504);
    float*          pl     = (float*)(w + 33 * MB);              // 1MB [4][NQT]
    unsigned short* pacc   = (unsigned short*)(w + 0 * MB);      // overlay 16MB (xh..yl dead)
    unsigned short* ahg    = qf;                                 // overlay (qf dead after attn)
    unsigned short* alg    = kf;

    // 1) bf16 hi/lo splits of x and y (one dispatch)
    split_bf16_xy<<<(2 * M * C / 8) / 256, 256, 0, stream>>>(x, y, xh, xl, yh, yl);

    // 2) weight transpose + split (one dispatch)
    prep_wt_all<<<1024, 256, 0, stream>>>(Wq, Wkv, Wo, Wqt_h, Wqt_l,
                                          Wkvt_h, Wkvt_l, Wot_h, Wot_l);

    // 3) projections with fused l2-norm epilogues -> fp16 qf / kf / vrow
    gemm_norm<0><<<dim3(M / 64, C / 64), 256, 0, stream>>>(
        xh, xl, Wqt_h, Wqt_l, temp, qf, nullptr);
    gemm_norm<1><<<dim3(M / 64, 2 * C / 64), 256, 0, stream>>>(
        yh, yl, Wkvt_h, Wkvt_l, temp, kf, vrow);

    // 4) V transpose (fp16 -> permuted fp16)
    vT_prep<<<dim3(L / 128, BH), 256, 0, stream>>>(vrow, vT);

    // 5) fp16 MFMA attention (pacc overlays dead xh..yl)
    attn_fp16<<<dim3(L / 128, BH, KSPLIT), 256, 0, stream>>>(qf, kf, vT, pacc, pl);

    // 6) combine splits -> bf16-split attnout (overlays qf/kf)
    combine_split<<<NQT / 256, 256, 0, stream>>>(pacc, pl, ahg, alg);

    // 7) output projection -> d_out
    gemm_mfma<<<dim3(M / 64, C / 64), 256, 0, stream>>>(ahg, alg, Wot_h, Wot_l, out, C);
}

// Round 8
// 168.580 us; speedup vs baseline: 13.5004x; 1.0995x over previous
//
#include <hip/hip_runtime.h>
#include <math.h>

// Problem constants
constexpr int B  = 2;
constexpr int L  = 4096;
constexpr int C  = 256;
constexpr int H  = 8;
constexpr int D  = 32;          // head dim
constexpr int M  = B * L;       // 8192 rows
constexpr int BH = B * H;       // 16
constexpr int KSPLIT = 4;
constexpr int NQT = BH * L;     // 65536
constexpr float LOG2E = 1.4426950408889634f;

typedef short    s8 __attribute__((ext_vector_type(8)));   // 8 bf16
typedef _Float16 h8 __attribute__((ext_vector_type(8)));   // 8 fp16
typedef __fp16   hp2 __attribute__((ext_vector_type(2)));  // cvt_pkrtz native type
typedef float    f4 __attribute__((ext_vector_type(4)));   // MFMA C/D

__device__ __forceinline__ unsigned short f2bf(float x) {
    unsigned u = __float_as_uint(x);
    u += 0x7fffu + ((u >> 16) & 1u);      // RNE
    return (unsigned short)(u >> 16);
}
__device__ __forceinline__ float bf2f(unsigned short h) {
    return __uint_as_float(((unsigned)h) << 16);
}
__device__ __forceinline__ unsigned pkrtz(float a, float b) {
    union { hp2 h; unsigned u; } c;
    c.h = __builtin_amdgcn_cvt_pkrtz(a, b);   // v_cvt_pkrtz_f16_f32
    return c.u;
}
__device__ __forceinline__ unsigned short f2h(float x) {
    union { _Float16 h; unsigned short u; } c; c.h = (_Float16)x; return c.u;  // RNE
}
__device__ __forceinline__ float h2f(unsigned short u) {
    union { _Float16 h; unsigned short u; } c; c.u = u; return (float)c.h;
}

// ---------------------------------------------------------------------------
// Split fp32 -> bf16 hi/lo for BOTH x and y in one dispatch. 8 elems/thread.
// ---------------------------------------------------------------------------
__global__ __launch_bounds__(256) void split_bf16_xy(
    const float* __restrict__ x, const float* __restrict__ y,
    unsigned short* __restrict__ xh, unsigned short* __restrict__ xl,
    unsigned short* __restrict__ yh, unsigned short* __restrict__ yl) {
    const int idx = blockIdx.x * 256 + threadIdx.x;   // 0..524287
    const float* in; unsigned short *oh, *ol; int i;
    if (idx < M * C / 8) { in = x; oh = xh; ol = xl; i = idx; }
    else                 { in = y; oh = yh; ol = yl; i = idx - M * C / 8; }
    float v[8];
    *reinterpret_cast<float4*>(&v[0]) = *reinterpret_cast<const float4*>(in + (size_t)i * 8);
    *reinterpret_cast<float4*>(&v[4]) = *reinterpret_cast<const float4*>(in + (size_t)i * 8 + 4);
    unsigned short hs[8], lo[8];
    #pragma unroll
    for (int j = 0; j < 8; ++j) {
        hs[j] = f2bf(v[j]);
        lo[j] = f2bf(v[j] - bf2f(hs[j]));
    }
    *reinterpret_cast<uint4*>(oh + (size_t)i * 8) = *reinterpret_cast<uint4*>(hs);
    *reinterpret_cast<uint4*>(ol + (size_t)i * 8) = *reinterpret_cast<uint4*>(lo);
}

// ---------------------------------------------------------------------------
// Transpose + bf16-split ALL THREE weight matrices in one dispatch.
// ---------------------------------------------------------------------------
__global__ __launch_bounds__(256) void prep_wt_all(
    const float* __restrict__ Wq, const float* __restrict__ Wkv, const float* __restrict__ Wo,
    unsigned short* __restrict__ Wqt_h, unsigned short* __restrict__ Wqt_l,
    unsigned short* __restrict__ Wkvt_h, unsigned short* __restrict__ Wkvt_l,
    unsigned short* __restrict__ Wot_h, unsigned short* __restrict__ Wot_l) {
    const int t = blockIdx.x * 256 + threadIdx.x;     // 0..262143
    const float* W; unsigned short *Oh, *Ol; int nlog2, idx;
    if (t < 65536)       { W = Wq;  Oh = Wqt_h;  Ol = Wqt_l;  nlog2 = 8; idx = t; }
    else if (t < 196608) { W = Wkv; Oh = Wkvt_h; Ol = Wkvt_l; nlog2 = 9; idx = t - 65536; }
    else                 { W = Wo;  Oh = Wot_h;  Ol = Wot_l;  nlog2 = 8; idx = t - 196608; }
    const int NN = 1 << nlog2;
    const int n = idx & (NN - 1);
    const int k = idx >> nlog2;          // 0..255
    const float w = W[(size_t)k * NN + n];
    const unsigned short h = f2bf(w);
    Oh[(size_t)n * 256 + k] = h;
    Ol[(size_t)n * 256 + k] = f2bf(w - bf2f(h));
}

// ---------------------------------------------------------------------------
// MERGED projection: one dispatch computes q (xh@Wqt) and kv (yh@Wkvt) with
// fused l2-norm epilogues. blockIdx.y: 0..3 -> q cols; 4..11 -> kv cols.
// Register-only bf16-split MFMA, wave tile 32x32 (one head per wave).
// ---------------------------------------------------------------------------
__global__ __launch_bounds__(256) void gemm_proj(
    const unsigned short* __restrict__ xh, const unsigned short* __restrict__ xl,
    const unsigned short* __restrict__ yh, const unsigned short* __restrict__ yl,
    const unsigned short* __restrict__ Wqt_h, const unsigned short* __restrict__ Wqt_l,
    const unsigned short* __restrict__ Wkvt_h, const unsigned short* __restrict__ Wkvt_l,
    const float* __restrict__ temp,
    unsigned short* __restrict__ qf, unsigned short* __restrict__ kf,
    unsigned short* __restrict__ vrow) {
    const int tid  = threadIdx.x;
    const int wv   = tid >> 6;
    const int lane = tid & 63;
    const int col  = lane & 15;
    const int grp  = lane >> 4;
    const int by   = blockIdx.y;
    const bool isq = (by < 4);
    const unsigned short* Ah = isq ? xh : yh;
    const unsigned short* Al = isq ? xl : yl;
    const unsigned short* Wh = isq ? Wqt_h : Wkvt_h;
    const unsigned short* Wl = isq ? Wqt_l : Wkvt_l;
    const int m_base = blockIdx.x * 64 + (wv >> 1) * 32;
    const int n_gl   = (isq ? by : by - 4) * 64 + (wv & 1) * 32;  // col offset in W-space

    const f4 fz = {0.f, 0.f, 0.f, 0.f};
    f4 acc[2][2] = {{fz, fz}, {fz, fz}};

    const size_t a0 = (size_t)(m_base + col) * 256;
    const size_t w0 = (size_t)(n_gl + col) * 256;

    #pragma unroll
    for (int k0 = 0; k0 < 256; k0 += 32) {
        const int ko = k0 + grp * 8;
        s8 ah[2], al[2], wh[2], wl[2];
        #pragma unroll
        for (int mt = 0; mt < 2; ++mt) {
            ah[mt] = *reinterpret_cast<const s8*>(Ah + a0 + (size_t)mt * 16 * 256 + ko);
            al[mt] = *reinterpret_cast<const s8*>(Al + a0 + (size_t)mt * 16 * 256 + ko);
        }
        #pragma unroll
        for (int nt = 0; nt < 2; ++nt) {
            wh[nt] = *reinterpret_cast<const s8*>(Wh + w0 + (size_t)nt * 16 * 256 + ko);
            wl[nt] = *reinterpret_cast<const s8*>(Wl + w0 + (size_t)nt * 16 * 256 + ko);
        }
        #pragma unroll
        for (int mt = 0; mt < 2; ++mt)
            #pragma unroll
            for (int nt = 0; nt < 2; ++nt) {
                acc[mt][nt] = __builtin_amdgcn_mfma_f32_16x16x32_bf16(ah[mt], wh[nt], acc[mt][nt], 0, 0, 0);
                acc[mt][nt] = __builtin_amdgcn_mfma_f32_16x16x32_bf16(al[mt], wh[nt], acc[mt][nt], 0, 0, 0);
                acc[mt][nt] = __builtin_amdgcn_mfma_f32_16x16x32_bf16(ah[mt], wl[nt], acc[mt][nt], 0, 0, 0);
            }
    }

    // epilogue: q -> norm*temp*LOG2E -> qf ; k -> norm -> kf ; v -> plain -> vrow
    const bool is_v = (!isq) && (n_gl >= 256);
    const int  nb   = is_v ? n_gl - 256 : n_gl;
    const int  h    = (nb >> 5) & 7;
    const float tl  = isq ? temp[h] * LOG2E : 1.0f;
    unsigned short* dst = isq ? qf : (is_v ? vrow : kf);

    #pragma unroll
    for (int mt = 0; mt < 2; ++mt)
        #pragma unroll
        for (int r = 0; r < 4; ++r) {
            float scale = 1.0f;
            if (!is_v) {
                float t = acc[mt][0][r] * acc[mt][0][r] + acc[mt][1][r] * acc[mt][1][r];
                t += __shfl_xor(t, 1);
                t += __shfl_xor(t, 2);
                t += __shfl_xor(t, 4);
                t += __shfl_xor(t, 8);
                scale = tl / fmaxf(sqrtf(t), 1e-12f);
            }
            const int row = m_base + mt * 16 + grp * 4 + r;
            const int bb = row >> 12, l = row & 4095;
            const size_t base = ((size_t)(bb * H + h) * L + l) * D;
            dst[base + col]      = f2h(acc[mt][0][r] * scale);
            dst[base + 16 + col] = f2h(acc[mt][1][r] * scale);
        }
}

// ---------------------------------------------------------------------------
// Plain register-only bf16-split MFMA GEMM (output projection), fp32 out.
// ---------------------------------------------------------------------------
__global__ __launch_bounds__(256) void gemm_mfma(
    const unsigned short* __restrict__ Ah, const unsigned short* __restrict__ Al,
    const unsigned short* __restrict__ Wth, const unsigned short* __restrict__ Wtl,
    float* __restrict__ out, int N) {
    const int tid  = threadIdx.x;
    const int wv   = tid >> 6;
    const int lane = tid & 63;
    const int col  = lane & 15;
    const int grp  = lane >> 4;
    const int m_base = blockIdx.x * 64 + (wv >> 1) * 32;
    const int n_base = blockIdx.y * 64 + (wv & 1) * 32;

    const f4 fz = {0.f, 0.f, 0.f, 0.f};
    f4 acc[2][2] = {{fz, fz}, {fz, fz}};

    const size_t a0 = (size_t)(m_base + col) * 256;
    const size_t w0 = (size_t)(n_base + col) * 256;

    #pragma unroll
    for (int k0 = 0; k0 < 256; k0 += 32) {
        const int ko = k0 + grp * 8;
        s8 ah[2], al[2], wh[2], wl[2];
        #pragma unroll
        for (int mt = 0; mt < 2; ++mt) {
            ah[mt] = *reinterpret_cast<const s8*>(Ah + a0 + (size_t)mt * 16 * 256 + ko);
            al[mt] = *reinterpret_cast<const s8*>(Al + a0 + (size_t)mt * 16 * 256 + ko);
        }
        #pragma unroll
        for (int nt = 0; nt < 2; ++nt) {
            wh[nt] = *reinterpret_cast<const s8*>(Wth + w0 + (size_t)nt * 16 * 256 + ko);
            wl[nt] = *reinterpret_cast<const s8*>(Wtl + w0 + (size_t)nt * 16 * 256 + ko);
        }
        #pragma unroll
        for (int mt = 0; mt < 2; ++mt)
            #pragma unroll
            for (int nt = 0; nt < 2; ++nt) {
                acc[mt][nt] = __builtin_amdgcn_mfma_f32_16x16x32_bf16(ah[mt], wh[nt], acc[mt][nt], 0, 0, 0);
                acc[mt][nt] = __builtin_amdgcn_mfma_f32_16x16x32_bf16(al[mt], wh[nt], acc[mt][nt], 0, 0, 0);
                acc[mt][nt] = __builtin_amdgcn_mfma_f32_16x16x32_bf16(ah[mt], wl[nt], acc[mt][nt], 0, 0, 0);
            }
    }

    #pragma unroll
    for (int mt = 0; mt < 2; ++mt)
        #pragma unroll
        for (int nt = 0; nt < 2; ++nt)
            #pragma unroll
            for (int r = 0; r < 4; ++r)
                out[(size_t)(m_base + mt * 16 + grp * 4 + r) * N + n_base + nt * 16 + col] =
                    acc[mt][nt][r];
}

// ---------------------------------------------------------------------------
// Build vT[bh][d][slot] fp16 from vrow[bh][l][32] (fp16) with the A-frag
// permutation: within each 32-key chunk, slot w <- key (w>>3)*4+((w&7)>>2)*16+(w&3).
// ---------------------------------------------------------------------------
__global__ __launch_bounds__(256) void vT_prep(const unsigned short* __restrict__ vrow,
                                               unsigned short* __restrict__ vT) {
    __shared__ unsigned short lt[32][136];   // [d][key_local] fp16 bits
    const int kb = blockIdx.x * 128;
    const int bh = blockIdx.y;
    const int t = threadIdx.x;

    {
        const int key = kb + (t >> 1);
        const int dh  = t & 1;
        const unsigned short* src = vrow + ((size_t)bh * L + key) * D + dh * 16;
        unsigned short tmp[16];
        *reinterpret_cast<uint4*>(&tmp[0]) = *reinterpret_cast<const uint4*>(src);
        *reinterpret_cast<uint4*>(&tmp[8]) = *reinterpret_cast<const uint4*>(src + 8);
        #pragma unroll
        for (int i = 0; i < 16; ++i)
            lt[dh * 16 + i][t >> 1] = tmp[i];
    }
    __syncthreads();
    {
        const int d  = t >> 3;
        const int sg = t & 7;
        unsigned ow[8];
        #pragma unroll
        for (int j = 0; j < 8; ++j) {
            int s0 = sg * 16 + 2 * j, s1 = s0 + 1;
            int w0 = s0 & 31, w1 = s1 & 31;
            int k0 = (s0 >> 5) * 32 + ((w0 >> 3) << 2) + (((w0 & 7) >> 2) << 4) + (w0 & 3);
            int k1 = (s1 >> 5) * 32 + ((w1 >> 3) << 2) + (((w1 & 7) >> 2) << 4) + (w1 & 3);
            ow[j] = (unsigned)lt[d][k0] | ((unsigned)lt[d][k1] << 16);
        }
        const size_t dst = ((size_t)(bh * D + d)) * L + kb + sg * 16;
        uint4 u0 = {ow[0], ow[1], ow[2], ow[3]};
        uint4 u1 = {ow[4], ow[5], ow[6], ow[7]};
        *reinterpret_cast<uint4*>(vT + dst)     = u0;
        *reinterpret_cast<uint4*>(vT + dst + 8) = u1;
    }
}

// ---------------------------------------------------------------------------
// fp16 MFMA flash attention, swapped-operand QK^T, register-resident P.
// 4 q-tiles per wave (64 q rows): K/V regs amortized over 4 QK+PV MFMAs.
// Explicit named double-buffer prefetch of next 32-key chunk (no dynamic
// register indexing). Grid (L/256, BH, KSPLIT).
// ---------------------------------------------------------------------------
#define LOADKV(KB0, KB1, VB0, VB1, KIDX) do {                               \
    const size_t ko_ = kbase + (size_t)((KIDX) + col) * D + grp * 8;        \
    KB0 = *reinterpret_cast<const h8*>(kf + ko_);                           \
    KB1 = *reinterpret_cast<const h8*>(kf + ko_ + 16 * D);                  \
    const size_t vo_ = kbase + (size_t)col * L + (KIDX) + grp * 8;          \
    VB0 = *reinterpret_cast<const h8*>(vT + vo_);                           \
    VB1 = *reinterpret_cast<const h8*>(vT + vo_ + 16 * L);                  \
} while (0)

#define CHUNK(KB0, KB1, VB0, VB1) do {                                      \
    _Pragma("unroll")                                                       \
    for (int qt = 0; qt < 4; ++qt) {                                        \
        f4 s0 = __builtin_amdgcn_mfma_f32_16x16x32_f16(KB0, qa[qt], fz, 0, 0, 0); \
        f4 s1 = __builtin_amdgcn_mfma_f32_16x16x32_f16(KB1, qa[qt], fz, 0, 0, 0); \
        float p[8];                                                         \
        _Pragma("unroll")                                                   \
        for (int r = 0; r < 4; ++r) {                                       \
            p[r]     = __builtin_amdgcn_exp2f(s0[r]);                       \
            p[r + 4] = __builtin_amdgcn_exp2f(s1[r]);                       \
        }                                                                   \
        ls[qt] += ((p[0] + p[1]) + (p[2] + p[3])) + ((p[4] + p[5]) + (p[6] + p[7])); \
        union { unsigned u[4]; h8 v; } pa;                                  \
        pa.u[0] = pkrtz(p[0], p[1]);                                        \
        pa.u[1] = pkrtz(p[2], p[3]);                                        \
        pa.u[2] = pkrtz(p[4], p[5]);                                        \
        pa.u[3] = pkrtz(p[6], p[7]);                                        \
        acc[qt][0] = __builtin_amdgcn_mfma_f32_16x16x32_f16(pa.v, VB0, acc[qt][0], 0, 0, 0); \
        acc[qt][1] = __builtin_amdgcn_mfma_f32_16x16x32_f16(pa.v, VB1, acc[qt][1], 0, 0, 0); \
    }                                                                       \
} while (0)

__global__ __launch_bounds__(256, 4) void attn_fp16(
    const unsigned short* __restrict__ qf, const unsigned short* __restrict__ kf,
    const unsigned short* __restrict__ vT,
    unsigned short* __restrict__ pacc,  // [KSPLIT][NQT][32] fp16
    float* __restrict__ pl) {           // [KSPLIT][NQT]
    const int qb = blockIdx.x, bh = blockIdx.y, sp = blockIdx.z;
    const int tid  = threadIdx.x;
    const int wv   = tid >> 6;
    const int lane = tid & 63;
    const int col  = lane & 15;
    const int grp  = lane >> 4;

    const int q0 = qb * 256 + wv * 64;
    h8 qa[4];
    #pragma unroll
    for (int qt = 0; qt < 4; ++qt)
        qa[qt] = *reinterpret_cast<const h8*>(
            qf + ((size_t)bh * L + q0 + qt * 16 + col) * D + grp * 8);

    const f4 fz = {0.f, 0.f, 0.f, 0.f};
    f4 acc[4][2] = {{fz, fz}, {fz, fz}, {fz, fz}, {fz, fz}};
    float ls[4] = {};

    const size_t kbase = (size_t)bh * L * D;
    const int kstart = sp * (L / KSPLIT);
    constexpr int SPAN = L / KSPLIT;    // 1024, multiple of 64

    h8 kA0, kA1, vA0, vA1, kB0, kB1, vB0, vB1;
    LOADKV(kA0, kA1, vA0, vA1, kstart);
    for (int c = 0; c < SPAN; c += 64) {
        LOADKV(kB0, kB1, vB0, vB1, kstart + c + 32);
        CHUNK(kA0, kA1, vA0, vA1);
        const int nx = (c + 64 < SPAN) ? (kstart + c + 64) : kstart;  // tail: dummy reload
        LOADKV(kA0, kA1, vA0, vA1, nx);
        CHUNK(kB0, kB1, vB0, vB1);
    }

    // denominators: each lane has partial for q = q0 + qt*16 + col over its
    // key subset; reduce across the 4 grp groups (lane bits 4,5)
    #pragma unroll
    for (int qt = 0; qt < 4; ++qt) {
        ls[qt] += __shfl_xor(ls[qt], 16);
        ls[qt] += __shfl_xor(ls[qt], 32);
    }

    const size_t pbase = (size_t)sp * NQT + (size_t)bh * L;
    if (lane < 16) {
        #pragma unroll
        for (int qt = 0; qt < 4; ++qt)
            pl[pbase + q0 + qt * 16 + lane] = ls[qt];
    }
    #pragma unroll
    for (int qt = 0; qt < 4; ++qt)
        #pragma unroll
        for (int dt = 0; dt < 2; ++dt)
            #pragma unroll
            for (int r = 0; r < 4; ++r) {
                const int q = q0 + qt * 16 + grp * 4 + r;
                pacc[(pbase + q) * D + dt * 16 + col] = f2h(acc[qt][dt][r]);
            }
}

// ---------------------------------------------------------------------------
// Combine 4 key-splits, normalize, write bf16-split attnout (feeds Wo GEMM).
// ---------------------------------------------------------------------------
__global__ __launch_bounds__(256) void combine_split(
    const unsigned short* __restrict__ pacc, const float* __restrict__ pl,
    unsigned short* __restrict__ ah, unsigned short* __restrict__ al) {
    const int q = blockIdx.x * 256 + threadIdx.x;      // bh*L + l
    float den = 0.f;
    #pragma unroll
    for (int sp = 0; sp < KSPLIT; ++sp) den += pl[(size_t)sp * NQT + q];
    const float inv = 1.0f / den;

    float o[D] = {};
    #pragma unroll
    for (int sp = 0; sp < KSPLIT; ++sp) {
        const unsigned short* a = pacc + ((size_t)sp * NQT + q) * D;
        unsigned short t[D];
        #pragma unroll
        for (int i = 0; i < 4; ++i)
            *reinterpret_cast<uint4*>(&t[i * 8]) = *reinterpret_cast<const uint4*>(a + i * 8);
        #pragma unroll
        for (int d = 0; d < D; ++d) o[d] += h2f(t[d]);
    }

    const int bh = q >> 12, lq = q & 4095;
    const int b = bh >> 3, h = bh & 7;
    unsigned short oh[D], ol[D];
    #pragma unroll
    for (int d = 0; d < D; ++d) {
        float v = o[d] * inv;
        oh[d] = f2bf(v);
        ol[d] = f2bf(v - bf2f(oh[d]));
    }
    const size_t dst = ((size_t)(b * L + lq)) * C + h * D;
    #pragma unroll
    for (int i = 0; i < 4; ++i) {
        *reinterpret_cast<uint4*>(ah + dst + i * 8) = *reinterpret_cast<uint4*>(&oh[i * 8]);
        *reinterpret_cast<uint4*>(al + dst + i * 8) = *reinterpret_cast<uint4*>(&ol[i * 8]);
    }
}

// ---------------------------------------------------------------------------
extern "C" void kernel_launch(void* const* d_in, const int* in_sizes, int n_in,
                              void* d_out, int out_size, void* d_ws, size_t ws_size,
                              hipStream_t stream) {
    const float* x    = (const float*)d_in[0];
    const float* y    = (const float*)d_in[1];
    const float* Wq   = (const float*)d_in[2];
    const float* Wkv  = (const float*)d_in[3];
    const float* Wo   = (const float*)d_in[4];
    const float* temp = (const float*)d_in[5];
    float* out = (float*)d_out;

    // workspace layout (1 MB = 1048576 B), max 34 MB
    char* w = (char*)d_ws;
    constexpr size_t MB = 1048576;
    unsigned short* xh     = (unsigned short*)(w + 0 * MB);      // 4MB each
    unsigned short* xl     = (unsigned short*)(w + 4 * MB);
    unsigned short* yh     = (unsigned short*)(w + 8 * MB);
    unsigned short* yl     = (unsigned short*)(w + 12 * MB);
    unsigned short* vrow   = (unsigned short*)(w + 16 * MB);     // 4MB fp16 [bh][l][32]
    unsigned short* qf     = (unsigned short*)(w + 20 * MB);     // 4MB
    unsigned short* kf     = (unsigned short*)(w + 24 * MB);     // 4MB
    unsigned short* vT     = (unsigned short*)(w + 28 * MB);     // 4MB
    unsigned short* Wqt_h  = (unsigned short*)(w + 32 * MB);          // 128KB
    unsigned short* Wqt_l  = (unsigned short*)(w + 32 * MB + 131072);
    unsigned short* Wkvt_h = (unsigned short*)(w + 32 * MB + 262144); // 256KB
    unsigned short* Wkvt_l = (unsigned short*)(w + 32 * MB + 524288);
    unsigned short* Wot_h  = (unsigned short*)(w + 32 * MB + 786432); // 128KB
    unsigned short* Wot_l  = (unsigned short*)(w + 32 * MB + 917504);
    float*          pl     = (float*)(w + 33 * MB);              // 1MB [4][NQT]
    unsigned short* pacc   = (unsigned short*)(w + 0 * MB);      // overlay 16MB (xh..yl dead)
    unsigned short* ahg    = qf;                                 // overlay (qf dead after attn)
    unsigned short* alg    = kf;

    // 1) bf16 hi/lo splits of x and y (one dispatch)
    split_bf16_xy<<<(2 * M * C / 8) / 256, 256, 0, stream>>>(x, y, xh, xl, yh, yl);

    // 2) weight transpose + split (one dispatch)
    prep_wt_all<<<1024, 256, 0, stream>>>(Wq, Wkv, Wo, Wqt_h, Wqt_l,
                                          Wkvt_h, Wkvt_l, Wot_h, Wot_l);

    // 3) merged projections with fused l2-norm epilogues -> fp16 qf/kf/vrow
    gemm_proj<<<dim3(M / 64, 12), 256, 0, stream>>>(
        xh, xl, yh, yl, Wqt_h, Wqt_l, Wkvt_h, Wkvt_l, temp, qf, kf, vrow);

    // 4) V transpose (fp16 -> permuted fp16)
    vT_prep<<<dim3(L / 128, BH), 256, 0, stream>>>(vrow, vT);

    // 5) fp16 MFMA attention, 64 q/wave, prefetched (pacc overlays dead xh..yl)
    attn_fp16<<<dim3(L / 256, BH, KSPLIT), 256, 0, stream>>>(qf, kf, vT, pacc, pl);

    // 6) combine splits -> bf16-split attnout (overlays qf/kf)
    combine_split<<<NQT / 256, 256, 0, stream>>>(pacc, pl, ahg, alg);

    // 7) output projection -> d_out
    gemm_mfma<<<dim3(M / 64, C / 64), 256, 0, stream>>>(ahg, alg, Wot_h, Wot_l, out, C);
}